// Round 9
// baseline (1649.881 us; speedup 1.0000x reference)
//
#include <hip/hip_runtime.h>
#include <hip/hip_bf16.h>
#include <type_traits>

// ---------------- CSR build ----------------
__global__ void hist_kernel(const int* __restrict__ src, const int* __restrict__ dst,
                            int* __restrict__ deg_out, int* __restrict__ deg_in, int E) {
    int e = blockIdx.x * blockDim.x + threadIdx.x;
    if (e < E) {
        atomicAdd(&deg_out[src[e]], 1);
        atomicAdd(&deg_in[dst[e]], 1);
    }
}

// single-block exclusive scan of deg (n) -> row_ptr[n+1], cursor copy
__global__ void scan_kernel(const int* __restrict__ deg, int* __restrict__ row_ptr,
                            int* __restrict__ cursor, int n) {
    __shared__ int wsum[16];
    __shared__ int running;
    int tid = threadIdx.x, lane = tid & 63, wid = tid >> 6;
    if (tid == 0) running = 0;
    __syncthreads();
    for (int base = 0; base < n; base += 1024) {
        int i = base + tid;
        int v = (i < n) ? deg[i] : 0;
        int incl = v;
        #pragma unroll
        for (int off = 1; off < 64; off <<= 1) {
            int t = __shfl_up(incl, off);
            if (lane >= off) incl += t;
        }
        if (lane == 63) wsum[wid] = incl;
        __syncthreads();
        if (wid == 0 && lane < 16) {
            int s = wsum[lane], si = s;
            #pragma unroll
            for (int off = 1; off < 16; off <<= 1) {
                int t = __shfl_up(si, off);
                if (lane >= off) si += t;
            }
            wsum[lane] = si - s;  // exclusive
        }
        __syncthreads();
        int excl = running + wsum[wid] + (incl - v);
        if (i < n) { row_ptr[i] = excl; cursor[i] = excl; }
        __syncthreads();
        if (tid == 1023) running = excl + v;
        __syncthreads();
    }
    if (tid == 0) row_ptr[n] = running;
}

__global__ void fill_kernel(const int* __restrict__ src, const int* __restrict__ dst,
                            int* __restrict__ cursor, int* __restrict__ col, int E) {
    int e = blockIdx.x * blockDim.x + threadIdx.x;
    if (e < E) {
        int p = atomicAdd(&cursor[dst[e]], 1);
        col[p] = src[e];
    }
}

// deterministic neighbor order: insertion-sort each CSR row (avg deg 16)
__global__ void sort_rows_kernel(const int* __restrict__ row_ptr, int* __restrict__ col, int n) {
    int v = blockIdx.x * blockDim.x + threadIdx.x;
    if (v >= n) return;
    int e0 = row_ptr[v], e1 = row_ptr[v + 1];
    for (int i = e0 + 1; i < e1; ++i) {
        int key = col[i];
        int j = i - 1;
        while (j >= e0 && col[j] > key) { col[j + 1] = col[j]; --j; }
        col[j + 1] = key;
    }
}

// ---------------- masked degrees ----------------
__global__ void out_deg_mask_kernel(const int* __restrict__ src, const int* __restrict__ dst,
                                    const float* __restrict__ m, float* __restrict__ so, int E) {
    int e = blockIdx.x * blockDim.x + threadIdx.x;
    if (e < E) {
        float md = m[dst[e]];
        if (md != 0.f) atomicAdd(&so[src[e]], md);
    }
}

__global__ void in_deg_mask_kernel(const int* __restrict__ row_ptr, const int* __restrict__ col,
                                   const float* __restrict__ m, float* __restrict__ si, int n) {
    int v = blockIdx.x * blockDim.x + threadIdx.x;
    if (v < n) {
        float s = 0.f;
        int e1 = row_ptr[v + 1];
        for (int e = row_ptr[v]; e < e1; ++e) s += m[col[e]];
        si[v] = s;
    }
}

__global__ void scale_full_kernel(const int* __restrict__ dout, const int* __restrict__ din,
                                  float* __restrict__ s, float* __restrict__ t, int n) {
    int v = blockIdx.x * blockDim.x + threadIdx.x;
    if (v < n) {
        s[v] = 1.f / sqrtf((float)max(dout[v], 1));
        t[v] = 1.f / sqrtf((float)max(din[v], 1));
    }
}

__global__ void scale_mask_kernel(const float* __restrict__ gate, const float* __restrict__ mask,
                                  const float* __restrict__ so, const float* __restrict__ si,
                                  float* __restrict__ s, float* __restrict__ t, int n) {
    int v = blockIdx.x * blockDim.x + threadIdx.x;
    if (v < n) {
        s[v] = gate[v] * (1.f / sqrtf(fmaxf(so[v], 1.f)));
        t[v] = mask[v] * (1.f / sqrtf(fmaxf(si[v], 1.f)));
    }
}

// ---------------- aggregation from f32 FEATURES, F=128 ----------------
__global__ void agg_feat_128_kernel(const int* __restrict__ row_ptr, const int* __restrict__ col,
                                    const float* __restrict__ X, const float* __restrict__ s,
                                    const float* __restrict__ t, float* __restrict__ out, int n) {
    int tid = threadIdx.x;
    int node = blockIdx.x * 8 + (tid >> 5);
    int f4 = tid & 31;
    if (node >= n) return;
    int e0 = row_ptr[node], e1 = row_ptr[node + 1];
    float ax = 0.f, ay = 0.f, az = 0.f, aw = 0.f;
    for (int e = e0; e < e1; ++e) {
        int u = col[e];
        float sc = s[u];
        if (sc != 0.f) {
            float4 q = ((const float4*)X)[(size_t)u * 32 + f4];
            ax += sc * q.x; ay += sc * q.y; az += sc * q.z; aw += sc * q.w;
        }
    }
    float tv = t[node];
    float4 r; r.x = ax * tv; r.y = ay * tv; r.z = az * tv; r.w = aw * tv;
    ((float4*)out)[(size_t)node * 32 + f4] = r;
}

// ---------------- aggregation over f32 workspace, F=256 ----------------
// Masked-dst skip: when t[node]==0 the following GEMM multiplies this row by
// the same mask (=0), so its content is irrelevant — skip the edge walk.
__global__ void agg_f32_256_kernel(const int* __restrict__ row_ptr, const int* __restrict__ col,
                                   const float* __restrict__ X, const float* __restrict__ s,
                                   const float* __restrict__ t, float* __restrict__ out, int n,
                                   int skip_masked) {
    int tid = threadIdx.x;
    int node = blockIdx.x * 4 + (tid >> 6);
    int f4 = tid & 63;
    if (node >= n) return;
    float tv = t[node];
    if (skip_masked && tv == 0.f) return;
    int e0 = row_ptr[node], e1 = row_ptr[node + 1];
    const float4* X4 = (const float4*)X;
    float ax = 0.f, ay = 0.f, az = 0.f, aw = 0.f;
    for (int e = e0; e < e1; ++e) {
        int u = col[e];
        float sc = s[u];
        if (sc != 0.f) {
            float4 xv = X4[(size_t)u * 64 + f4];
            ax += sc * xv.x; ay += sc * xv.y; az += sc * xv.z; aw += sc * xv.w;
        }
    }
    float4 r; r.x = ax * tv; r.y = ay * tv; r.z = az * tv; r.w = aw * tv;
    ((float4*)out)[(size_t)node * 64 + f4] = r;
}

// ---------------- GEMM: out[M,Nn] = act(A[M,K] @ W[K,Nn] + b) * mask ----------------
// 128x128 block tile, 8x8 per-thread micro-tile (R9: old 64x64/4x4 was
// LDS-BW-bound at ~52 TF; 8x8 gives 64 FLOP per 4 ds_read_b128 -> VALU-bound).
// K accumulation order (k0 outer, kk inner, sequential) is IDENTICAL to the
// old kernel -> bit-identical outputs, top-k sets unchanged.
template <bool RELU>
__global__ __launch_bounds__(256) void gemm_kernel(const float* __restrict__ A,
                                                   const float* __restrict__ W,
                                                   const float* __restrict__ bias,
                                                   const float* __restrict__ mask,
                                                   float* __restrict__ C, int M, int K, int Nn) {
    __shared__ float As[16][132];
    __shared__ float Bs[16][132];
    int tid = threadIdx.x;
    int bm = blockIdx.x * 128, bn = blockIdx.y * 128;
    int mA = tid >> 1, kqA = (tid & 1) * 8;      // A stage: 128 rows x 16 k
    int kB = tid >> 4, nqB = (tid & 15) * 8;     // B stage: 16 k x 128 n
    int tm = (tid >> 4) * 8, tn = (tid & 15) * 8;
    float acc[8][8] = {};
    int rA = bm + mA; if (rA >= M) rA = M - 1;   // clamp: padded rows never stored
    for (int k0 = 0; k0 < K; k0 += 16) {
        const float* ap = A + (size_t)rA * K + k0 + kqA;
        float4 a0 = *(const float4*)ap;
        float4 a1 = *(const float4*)(ap + 4);
        As[kqA + 0][mA] = a0.x; As[kqA + 1][mA] = a0.y;
        As[kqA + 2][mA] = a0.z; As[kqA + 3][mA] = a0.w;
        As[kqA + 4][mA] = a1.x; As[kqA + 5][mA] = a1.y;
        As[kqA + 6][mA] = a1.z; As[kqA + 7][mA] = a1.w;
        const float* wp = W + (size_t)(k0 + kB) * Nn + bn + nqB;
        *(float4*)&Bs[kB][nqB]     = *(const float4*)wp;
        *(float4*)&Bs[kB][nqB + 4] = *(const float4*)(wp + 4);
        __syncthreads();
        #pragma unroll
        for (int kk = 0; kk < 16; ++kk) {
            float4 av0 = *(const float4*)&As[kk][tm];
            float4 av1 = *(const float4*)&As[kk][tm + 4];
            float4 bv0 = *(const float4*)&Bs[kk][tn];
            float4 bv1 = *(const float4*)&Bs[kk][tn + 4];
            float ar[8] = {av0.x, av0.y, av0.z, av0.w, av1.x, av1.y, av1.z, av1.w};
            float br[8] = {bv0.x, bv0.y, bv0.z, bv0.w, bv1.x, bv1.y, bv1.z, bv1.w};
            #pragma unroll
            for (int i2 = 0; i2 < 8; i2++)
                #pragma unroll
                for (int j = 0; j < 8; j++) acc[i2][j] += ar[i2] * br[j];
        }
        __syncthreads();
    }
    #pragma unroll
    for (int i2 = 0; i2 < 8; i2++) {
        int row = bm + tm + i2;
        if (row < M) {
            float mv = mask ? mask[row] : 1.f;
            float o[8];
            #pragma unroll
            for (int j = 0; j < 8; j++) {
                float x = acc[i2][j] + bias[bn + tn + j];
                if (RELU) x = fmaxf(x, 0.f);
                o[j] = x * mv;
            }
            float* cp = C + (size_t)row * Nn + bn + tn;
            *(float4*)cp       = make_float4(o[0], o[1], o[2], o[3]);
            *(float4*)(cp + 4) = make_float4(o[4], o[5], o[6], o[7]);
        }
    }
}

// ---------------- pooling score: sigmoid(h . wp + bp) ----------------
__global__ void score_kernel(const float* __restrict__ H, const float* __restrict__ Wp,
                             const float* __restrict__ bp, const float* __restrict__ mask,
                             float* __restrict__ scores, float* __restrict__ keys, int n) {
    int lane = threadIdx.x & 63;
    int node = blockIdx.x * 4 + (threadIdx.x >> 6);
    if (node >= n) return;
    float4 hv = ((const float4*)(H + (size_t)node * 256))[lane];
    float4 wq = ((const float4*)Wp)[lane];
    float d = hv.x * wq.x + hv.y * wq.y + hv.z * wq.z + hv.w * wq.w;
    #pragma unroll
    for (int off = 32; off > 0; off >>= 1) d += __shfl_down(d, off);
    if (lane == 0) {
        float sc = 1.f / (1.f + expf(-(d + bp[0])));
        scores[node] = sc;
        keys[node] = (mask && mask[node] == 0.f) ? -1e9f : sc;
    }
}

// ---------------- top-K selection ----------------
__device__ __forceinline__ unsigned key_u(float f) {
    unsigned u = __float_as_uint(f);
    return (u & 0x80000000u) ? ~u : (u | 0x80000000u);
}

// Wave-aggregated histogram increment (R7 win: clustered keys serialize naive
// atomics; leader adds popcount once per distinct bin per wave).
__device__ __forceinline__ void wave_hist_add(int* __restrict__ hist, unsigned bin, bool valid) {
    int lane = threadIdx.x & 63;
    while (true) {
        unsigned long long vmask = __ballot(valid);
        if (vmask == 0ull) break;
        int leader = __ffsll((long long)vmask) - 1;
        unsigned lbin = (unsigned)__shfl((int)bin, leader);
        bool match = valid && (bin == lbin);
        unsigned long long mmask = __ballot(match);
        if (lane == leader) atomicAdd(&hist[lbin], __popcll(mmask));
        if (match) valid = false;
    }
}

// -------- fallback: single block radix select (known-good R2/R5) --------
__global__ void topk_kernel(const float* __restrict__ keys, const float* __restrict__ scores,
                            float* __restrict__ nm, float* __restrict__ gate, int n, int K) {
    __shared__ int hist[256];
    __shared__ unsigned sh_prefix;
    __shared__ int sh_krem;
    __shared__ int sh_running;
    __shared__ int wsum[16];
    int tid = threadIdx.x, lane = tid & 63, wid = tid >> 6;
    if (tid == 0) { sh_prefix = 0u; sh_krem = K; sh_running = 0; }
    __syncthreads();
    for (int pass = 0; pass < 4; ++pass) {
        int shift = 24 - pass * 8;
        if (tid < 256) hist[tid] = 0;
        __syncthreads();
        unsigned pmask = (pass == 0) ? 0u : (0xFFFFFFFFu << (shift + 8));
        unsigned prefix = sh_prefix;
        for (int i = tid; i < n; i += 1024) {
            unsigned u = key_u(keys[i]);
            if ((u & pmask) == prefix) atomicAdd(&hist[(u >> shift) & 0xFF], 1);
        }
        __syncthreads();
        if (tid == 0) {
            int krem = sh_krem;
            int b;
            for (b = 255; b > 0; --b) {
                int c = hist[b];
                if (c >= krem) break;
                krem -= c;
            }
            sh_prefix = prefix | ((unsigned)b << shift);
            sh_krem = krem;
        }
        __syncthreads();
    }
    unsigned Tkey = sh_prefix;
    int need_eq = sh_krem;
    for (int base = 0; base < n; base += 1024) {
        int i = base + tid;
        unsigned u = 0; int flagv = 0;
        if (i < n) { u = key_u(keys[i]); flagv = (u == Tkey) ? 1 : 0; }
        unsigned long long bal = __ballot(flagv);
        int rank_w = __popcll(bal & ((1ull << lane) - 1ull));
        if (lane == 63) wsum[wid] = __popcll(bal);
        __syncthreads();
        int woff = 0;
        for (int w = 0; w < wid; ++w) woff += wsum[w];
        int grank = sh_running + woff + rank_w;
        if (i < n) {
            float v = (u > Tkey) ? 1.f : ((flagv && grank < need_eq) ? 1.f : 0.f);
            nm[i] = v;
            gate[i] = v * scores[i];
        }
        __syncthreads();
        if (tid == 0) {
            int tot = 0;
            for (int w = 0; w < 16; ++w) tot += wsum[w];
            sh_running += tot;
        }
        __syncthreads();
    }
}

// -------- fast path: grid-wide radix select, 2 passes of 16 bits --------
__global__ void topk_hist1(const float* __restrict__ keys, int n, int* __restrict__ hist) {
    int i = blockIdx.x * blockDim.x + threadIdx.x;
    unsigned bin = 0; bool valid = (i < n);
    if (valid) bin = key_u(keys[i]) >> 16;
    wave_hist_add(hist, bin, valid);
}

// single block (1024 thr): suffix-scan 64K bins; sel[0]=bucket, sel[1]=krem
__global__ void topk_scan1(const int* __restrict__ hist, int K, int* __restrict__ sel) {
    __shared__ int arr[1024];
    int tid = threadIdx.x;
    int base = tid * 64;
    int local = 0;
    #pragma unroll 8
    for (int b = 0; b < 64; ++b) local += hist[base + b];
    arr[tid] = local;
    __syncthreads();
    for (int off = 1; off < 1024; off <<= 1) {
        int v = (tid + off < 1024) ? arr[tid + off] : 0;
        __syncthreads();
        arr[tid] += v;
        __syncthreads();
    }
    int above = arr[tid] - local;       // suffix(tid+1)
    if (above < K && arr[tid] >= K) {   // unique: arr strictly decreasing in tid
        int run = above;
        for (int b = base + 63; b >= base; --b) {
            int c = hist[b];
            if (run + c >= K) { sel[0] = b; sel[1] = K - run; break; }
            run += c;
        }
    }
}

__global__ void topk_hist2(const float* __restrict__ keys, int n, const int* __restrict__ sel,
                           int* __restrict__ hist) {
    int i = blockIdx.x * blockDim.x + threadIdx.x;
    unsigned bin = 0; bool valid = false;
    if (i < n) {
        unsigned u = key_u(keys[i]);
        if ((int)(u >> 16) == sel[0]) { bin = u & 0xFFFF; valid = true; }
    }
    wave_hist_add(hist, bin, valid);
}

// single block: sel[2]=Tkey, sel[3]=need_eq; resets tie counter
__global__ void topk_scan2(const int* __restrict__ hist, int* __restrict__ sel,
                           int* __restrict__ tie_cnt) {
    __shared__ int arr[1024];
    int tid = threadIdx.x;
    if (tid == 0) *tie_cnt = 0;
    int K = sel[1];
    int base = tid * 64;
    int local = 0;
    #pragma unroll 8
    for (int b = 0; b < 64; ++b) local += hist[base + b];
    arr[tid] = local;
    __syncthreads();
    for (int off = 1; off < 1024; off <<= 1) {
        int v = (tid + off < 1024) ? arr[tid + off] : 0;
        __syncthreads();
        arr[tid] += v;
        __syncthreads();
    }
    int above = arr[tid] - local;
    if (above < K && arr[tid] >= K) {
        int run = above;
        for (int b = base + 63; b >= base; --b) {
            int c = hist[b];
            if (run + c >= K) {
                sel[2] = (int)((((unsigned)sel[0]) << 16) | (unsigned)b);
                sel[3] = K - run;
                break;
            }
            run += c;
        }
    }
}

// grid-wide mark: strictly-above selected; equal-to-threshold -> tie list
__global__ void topk_mark(const float* __restrict__ keys, const float* __restrict__ scores,
                          const int* __restrict__ sel, float* __restrict__ nm,
                          float* __restrict__ gate, int* __restrict__ tie_list,
                          int* __restrict__ tie_cnt, int n) {
    int i = blockIdx.x * blockDim.x + threadIdx.x;
    if (i >= n) return;
    unsigned Tkey = (unsigned)sel[2];
    unsigned u = key_u(keys[i]);
    float v = 0.f;
    if (u > Tkey) v = 1.f;
    else if (u == Tkey) { int p = atomicAdd(tie_cnt, 1); tie_list[p] = i; }
    nm[i] = v;
    gate[i] = v * scores[i];
}

// single block: ties resolved lowest-index-first (rank by index value ->
// independent of nondeterministic tie_list order)
__global__ void topk_ties(const float* __restrict__ scores, const int* __restrict__ sel,
                          const int* __restrict__ tie_list, const int* __restrict__ tie_cnt,
                          float* __restrict__ nm, float* __restrict__ gate) {
    int cnt = *tie_cnt;
    int need = sel[3];
    for (int j = threadIdx.x; j < cnt; j += blockDim.x) {
        int idx = tie_list[j];
        int rank = 0;
        for (int k2 = 0; k2 < cnt; ++k2) rank += (tie_list[k2] < idx) ? 1 : 0;
        if (rank < need) { nm[idx] = 1.f; gate[idx] = scores[idx]; }
    }
}

// ---------------- elementwise add: A += B ----------------
__global__ void add_kernel(float* __restrict__ A, const float* __restrict__ B, int n4) {
    int i = blockIdx.x * blockDim.x + threadIdx.x;
    if (i < n4) {
        float4 a = ((float4*)A)[i];
        float4 b = ((const float4*)B)[i];
        a.x += b.x; a.y += b.y; a.z += b.z; a.w += b.w;
        ((float4*)A)[i] = a;
    }
}

extern "C" void kernel_launch(void* const* d_in, const int* in_sizes, int n_in,
                              void* d_out, int out_size, void* d_ws, size_t ws_size,
                              hipStream_t stream) {
    const int n = in_sizes[0] / 128;   // 50000
    const int E = in_sizes[1];         // 800000
    const int NPAD = ((n + 63) / 64) * 64;
    const int K1 = 25000, K2 = 12500;

    const float* features = (const float*)d_in[0];
    const int* src = (const int*)d_in[1];
    const int* dst = (const int*)d_in[2];
    const float* W_embed = (const float*)d_in[3];
    const float* b_embed = (const float*)d_in[4];
    const float* W_enc0  = (const float*)d_in[5];
    const float* b_enc0  = (const float*)d_in[6];
    const float* W_enc1  = (const float*)d_in[7];
    const float* b_enc1  = (const float*)d_in[8];
    const float* W_p0    = (const float*)d_in[9];
    const float* b_p0    = (const float*)d_in[10];
    const float* W_p1    = (const float*)d_in[11];
    const float* b_p1    = (const float*)d_in[12];
    const float* W_bot   = (const float*)d_in[13];
    const float* b_bot   = (const float*)d_in[14];
    const float* W_dec0  = (const float*)d_in[15];
    const float* b_dec0  = (const float*)d_in[16];
    const float* W_dec1  = (const float*)d_in[17];
    const float* b_dec1  = (const float*)d_in[18];
    float* out_f = (float*)d_out;

    char* ws = (char*)d_ws;
    size_t off = 0;
    auto alloc = [&](size_t bytes) -> void* {
        void* p = ws + off;
        off += (bytes + 255) & ~(size_t)255;
        return p;
    };
    (void)alloc(256);  // pad (R2 'flag' slot)
    int* row_ptr  = (int*)alloc((size_t)(n + 1) * 4);
    int* cursor   = (int*)alloc((size_t)n * 4);
    int* col      = (int*)alloc((size_t)E * 4);
    int* deg_out_i= (int*)alloc((size_t)n * 4);
    int* deg_in_i = (int*)alloc((size_t)n * 4);
    float* so_m1  = (float*)alloc((size_t)n * 4);
    float* si_m1  = (float*)alloc((size_t)n * 4);
    float* so_m2  = (float*)alloc((size_t)n * 4);
    float* si_m2  = (float*)alloc((size_t)n * 4);
    float* sarr   = (float*)alloc((size_t)n * 4);
    float* tarr   = (float*)alloc((size_t)n * 4);
    float* scores1= (float*)alloc((size_t)n * 4);
    float* keys1  = (float*)alloc((size_t)n * 4);
    float* scores2= (float*)alloc((size_t)n * 4);
    float* keys2  = (float*)alloc((size_t)n * 4);
    float* nm1    = (float*)alloc((size_t)n * 4);
    float* gate1  = (float*)alloc((size_t)n * 4);
    float* nm2    = (float*)alloc((size_t)n * 4);
    float* gate2  = (float*)alloc((size_t)n * 4);
    size_t big = (size_t)NPAD * 256 * 4;
    float* A = (float*)alloc(big);
    float* B = (float*)alloc(big);
    float* C = (float*)alloc(big);
    float* D = (float*)alloc(big);
    // ---- tail ----
    int* rhist    = (int*)alloc(65536 * 4);
    int* sel      = (int*)alloc(256);
    int* tie_cnt  = (int*)alloc(256);
    int* tie_list = (int*)alloc((size_t)n * 4);
    float* s0     = (float*)alloc((size_t)n * 4);
    float* t0     = (float*)alloc((size_t)n * 4);
    bool fast = (off <= ws_size);   // host-constant: same decision every call

    dim3 blk(256);
    int gE = (E + 255) / 256;
    int gN = (n + 255) / 256;
    int gAgg256 = (n + 3) / 4;
    int gAgg128 = (n + 7) / 8;
    int gScore = (n + 3) / 4;
    dim3 gemm_g((NPAD + 127) / 128, 2);
    dim3 gemm_g128((NPAD + 127) / 128, 1);
    int gAdd = (n * 64 + 255) / 256;

    auto run_topk = [&](const float* keys, const float* scores, float* nm, float* gate, int K) {
        if (fast) {
            hipMemsetAsync(rhist, 0, 65536 * 4, stream);
            topk_hist1<<<gN, blk, 0, stream>>>(keys, n, rhist);
            topk_scan1<<<1, 1024, 0, stream>>>(rhist, K, sel);
            hipMemsetAsync(rhist, 0, 65536 * 4, stream);
            topk_hist2<<<gN, blk, 0, stream>>>(keys, n, sel, rhist);
            topk_scan2<<<1, 1024, 0, stream>>>(rhist, sel, tie_cnt);
            topk_mark<<<gN, blk, 0, stream>>>(keys, scores, sel, nm, gate, tie_list, tie_cnt, n);
            topk_ties<<<1, 256, 0, stream>>>(scores, sel, tie_list, tie_cnt, nm, gate);
        } else {
            topk_kernel<<<1, 1024, 0, stream>>>(keys, scores, nm, gate, n, K);
        }
    };
    float* sF = fast ? s0 : sarr;
    float* tF = fast ? t0 : tarr;

    // ---- CSR build ----
    hipMemsetAsync(deg_out_i, 0, (size_t)n * 4, stream);
    hipMemsetAsync(deg_in_i, 0, (size_t)n * 4, stream);
    hist_kernel<<<gE, blk, 0, stream>>>(src, dst, deg_out_i, deg_in_i, E);
    scan_kernel<<<1, 1024, 0, stream>>>(deg_in_i, row_ptr, cursor, n);
    fill_kernel<<<gE, blk, 0, stream>>>(src, dst, cursor, col, E);
    sort_rows_kernel<<<gN, blk, 0, stream>>>(row_ptr, col, n);

    // ---- full-graph degree scales (once) ----
    scale_full_kernel<<<gN, blk, 0, stream>>>(deg_out_i, deg_in_i, sF, tF, n);

    // ---- embed GCN (full graph) -> A ----
    agg_feat_128_kernel<<<gAgg128, blk, 0, stream>>>(row_ptr, col, features, sF, tF, D, n);
    gemm_kernel<true><<<gemm_g, blk, 0, stream>>>(D, W_embed, b_embed, nullptr, A, n, 128, 256);

    // ---- enc0 (full graph); hidden0 = B ----
    agg_f32_256_kernel<<<gAgg256, blk, 0, stream>>>(row_ptr, col, A, sF, tF, D, n, 0);
    gemm_kernel<true><<<gemm_g, blk, 0, stream>>>(D, W_enc0, b_enc0, nullptr, B, n, 256, 256);

    // ---- pool0 ----
    score_kernel<<<gScore, blk, 0, stream>>>(B, W_p0, b_p0, nullptr, scores1, keys1, n);
    run_topk(keys1, scores1, nm1, gate1, K1);

    // ---- enc1 (mask m1, gated input); hidden1 = C ----
    hipMemsetAsync(so_m1, 0, (size_t)n * 4, stream);
    out_deg_mask_kernel<<<gE, blk, 0, stream>>>(src, dst, nm1, so_m1, E);
    in_deg_mask_kernel<<<gN, blk, 0, stream>>>(row_ptr, col, nm1, si_m1, n);
    scale_mask_kernel<<<gN, blk, 0, stream>>>(gate1, nm1, so_m1, si_m1, sarr, tarr, n);
    agg_f32_256_kernel<<<gAgg256, blk, 0, stream>>>(row_ptr, col, B, sarr, tarr, D, n, 1);
    gemm_kernel<true><<<gemm_g, blk, 0, stream>>>(D, W_enc1, b_enc1, nm1, C, n, 256, 256);

    // ---- pool1 ----
    score_kernel<<<gScore, blk, 0, stream>>>(C, W_p1, b_p1, nm1, scores2, keys2, n);
    run_topk(keys2, scores2, nm2, gate2, K2);

    // ---- bottleneck (mask m2, gated input) -> A ----
    hipMemsetAsync(so_m2, 0, (size_t)n * 4, stream);
    out_deg_mask_kernel<<<gE, blk, 0, stream>>>(src, dst, nm2, so_m2, E);
    in_deg_mask_kernel<<<gN, blk, 0, stream>>>(row_ptr, col, nm2, si_m2, n);
    scale_mask_kernel<<<gN, blk, 0, stream>>>(gate2, nm2, so_m2, si_m2, sarr, tarr, n);
    agg_f32_256_kernel<<<gAgg256, blk, 0, stream>>>(row_ptr, col, C, sarr, tarr, D, n, 1);
    gemm_kernel<true><<<gemm_g, blk, 0, stream>>>(D, W_bot, b_bot, nm2, A, n, 256, 256);

    // ---- dec0: h = bot + hidden1, GCN mask m1 -> A ----
    add_kernel<<<gAdd, blk, 0, stream>>>(A, C, n * 64);
    scale_mask_kernel<<<gN, blk, 0, stream>>>(nm1, nm1, so_m1, si_m1, sarr, tarr, n);
    agg_f32_256_kernel<<<gAgg256, blk, 0, stream>>>(row_ptr, col, A, sarr, tarr, D, n, 1);
    gemm_kernel<true><<<gemm_g, blk, 0, stream>>>(D, W_dec0, b_dec0, nm1, A, n, 256, 256);

    // ---- dec1: h = dec0 + hidden0, GCN full graph, no relu -> d_out (f32) ----
    add_kernel<<<gAdd, blk, 0, stream>>>(A, B, n * 64);
    if (!fast)
        scale_full_kernel<<<gN, blk, 0, stream>>>(deg_out_i, deg_in_i, sarr, tarr, n);
    agg_f32_256_kernel<<<gAgg256, blk, 0, stream>>>(row_ptr, col, A, sF, tF, D, n, 0);
    gemm_kernel<false><<<gemm_g128, blk, 0, stream>>>(D, W_dec1, b_dec1, nullptr, out_f, n, 256, 128);

    (void)n_in; (void)out_size;
}

// Round 10
// 1506.301 us; speedup vs baseline: 1.0953x; 1.0953x over previous
//
#include <hip/hip_runtime.h>
#include <hip/hip_bf16.h>
#include <type_traits>

// ---------------- CSR build ----------------
__global__ void hist_kernel(const int* __restrict__ src, const int* __restrict__ dst,
                            int* __restrict__ deg_out, int* __restrict__ deg_in, int E) {
    int e = blockIdx.x * blockDim.x + threadIdx.x;
    if (e < E) {
        atomicAdd(&deg_out[src[e]], 1);
        atomicAdd(&deg_in[dst[e]], 1);
    }
}

// single-block exclusive scan of deg (n) -> row_ptr[n+1], cursor copy
__global__ void scan_kernel(const int* __restrict__ deg, int* __restrict__ row_ptr,
                            int* __restrict__ cursor, int n) {
    __shared__ int wsum[16];
    __shared__ int running;
    int tid = threadIdx.x, lane = tid & 63, wid = tid >> 6;
    if (tid == 0) running = 0;
    __syncthreads();
    for (int base = 0; base < n; base += 1024) {
        int i = base + tid;
        int v = (i < n) ? deg[i] : 0;
        int incl = v;
        #pragma unroll
        for (int off = 1; off < 64; off <<= 1) {
            int t = __shfl_up(incl, off);
            if (lane >= off) incl += t;
        }
        if (lane == 63) wsum[wid] = incl;
        __syncthreads();
        if (wid == 0 && lane < 16) {
            int s = wsum[lane], si = s;
            #pragma unroll
            for (int off = 1; off < 16; off <<= 1) {
                int t = __shfl_up(si, off);
                if (lane >= off) si += t;
            }
            wsum[lane] = si - s;  // exclusive
        }
        __syncthreads();
        int excl = running + wsum[wid] + (incl - v);
        if (i < n) { row_ptr[i] = excl; cursor[i] = excl; }
        __syncthreads();
        if (tid == 1023) running = excl + v;
        __syncthreads();
    }
    if (tid == 0) row_ptr[n] = running;
}

__global__ void fill_kernel(const int* __restrict__ src, const int* __restrict__ dst,
                            int* __restrict__ cursor, int* __restrict__ col, int E) {
    int e = blockIdx.x * blockDim.x + threadIdx.x;
    if (e < E) {
        int p = atomicAdd(&cursor[dst[e]], 1);
        col[p] = src[e];
    }
}

// deterministic neighbor order: insertion-sort each CSR row (avg deg 16)
__global__ void sort_rows_kernel(const int* __restrict__ row_ptr, int* __restrict__ col, int n) {
    int v = blockIdx.x * blockDim.x + threadIdx.x;
    if (v >= n) return;
    int e0 = row_ptr[v], e1 = row_ptr[v + 1];
    for (int i = e0 + 1; i < e1; ++i) {
        int key = col[i];
        int j = i - 1;
        while (j >= e0 && col[j] > key) { col[j + 1] = col[j]; --j; }
        col[j + 1] = key;
    }
}

// ---------------- masked degrees ----------------
__global__ void out_deg_mask_kernel(const int* __restrict__ src, const int* __restrict__ dst,
                                    const float* __restrict__ m, float* __restrict__ so, int E) {
    int e = blockIdx.x * blockDim.x + threadIdx.x;
    if (e < E) {
        float md = m[dst[e]];
        if (md != 0.f) atomicAdd(&so[src[e]], md);
    }
}

__global__ void in_deg_mask_kernel(const int* __restrict__ row_ptr, const int* __restrict__ col,
                                   const float* __restrict__ m, float* __restrict__ si, int n) {
    int v = blockIdx.x * blockDim.x + threadIdx.x;
    if (v < n) {
        float s = 0.f;
        int e1 = row_ptr[v + 1];
        for (int e = row_ptr[v]; e < e1; ++e) s += m[col[e]];
        si[v] = s;
    }
}

__global__ void scale_full_kernel(const int* __restrict__ dout, const int* __restrict__ din,
                                  float* __restrict__ s, float* __restrict__ t, int n) {
    int v = blockIdx.x * blockDim.x + threadIdx.x;
    if (v < n) {
        s[v] = 1.f / sqrtf((float)max(dout[v], 1));
        t[v] = 1.f / sqrtf((float)max(din[v], 1));
    }
}

__global__ void scale_mask_kernel(const float* __restrict__ gate, const float* __restrict__ mask,
                                  const float* __restrict__ so, const float* __restrict__ si,
                                  float* __restrict__ s, float* __restrict__ t, int n) {
    int v = blockIdx.x * blockDim.x + threadIdx.x;
    if (v < n) {
        s[v] = gate[v] * (1.f / sqrtf(fmaxf(so[v], 1.f)));
        t[v] = mask[v] * (1.f / sqrtf(fmaxf(si[v], 1.f)));
    }
}

// ---------------- aggregation from f32 FEATURES, F=128 (full graph: s never 0) ----------------
// R10: guard removed (full-graph scales > 0) + 4x edge unroll with grouped
// loads -> 4 gathers in flight. Accumulation order over e unchanged ->
// bit-identical output.
__global__ void agg_feat_128_kernel(const int* __restrict__ row_ptr, const int* __restrict__ col,
                                    const float* __restrict__ X, const float* __restrict__ s,
                                    const float* __restrict__ t, float* __restrict__ out, int n) {
    int tid = threadIdx.x;
    int node = blockIdx.x * 8 + (tid >> 5);
    int f4 = tid & 31;
    if (node >= n) return;
    int e0 = row_ptr[node], e1 = row_ptr[node + 1];
    const float4* X4 = (const float4*)X;
    float ax = 0.f, ay = 0.f, az = 0.f, aw = 0.f;
    int e = e0;
    for (; e + 3 < e1; e += 4) {
        int u0 = col[e], u1 = col[e + 1], u2 = col[e + 2], u3 = col[e + 3];
        float s0 = s[u0], s1 = s[u1], s2 = s[u2], s3 = s[u3];
        float4 x0 = X4[(size_t)u0 * 32 + f4];
        float4 x1 = X4[(size_t)u1 * 32 + f4];
        float4 x2 = X4[(size_t)u2 * 32 + f4];
        float4 x3 = X4[(size_t)u3 * 32 + f4];
        ax += s0 * x0.x; ay += s0 * x0.y; az += s0 * x0.z; aw += s0 * x0.w;
        ax += s1 * x1.x; ay += s1 * x1.y; az += s1 * x1.z; aw += s1 * x1.w;
        ax += s2 * x2.x; ay += s2 * x2.y; az += s2 * x2.z; aw += s2 * x2.w;
        ax += s3 * x3.x; ay += s3 * x3.y; az += s3 * x3.z; aw += s3 * x3.w;
    }
    for (; e < e1; ++e) {
        int u = col[e];
        float sc = s[u];
        float4 q = X4[(size_t)u * 32 + f4];
        ax += sc * q.x; ay += sc * q.y; az += sc * q.z; aw += sc * q.w;
    }
    float tv = t[node];
    float4 r; r.x = ax * tv; r.y = ay * tv; r.z = az * tv; r.w = aw * tv;
    ((float4*)out)[(size_t)node * 32 + f4] = r;
}

// ---------------- aggregation over f32 workspace, F=256 ----------------
// MASKED=false (full graph): no guards, 4x unroll, 4 gathers in flight.
// MASKED=true: t==0 row skip + s!=0 guards (the traffic saver), guarded 4x
// unroll. Both preserve e-order accumulation -> bit-identical.
template <bool MASKED>
__global__ void agg_f32_256_kernel(const int* __restrict__ row_ptr, const int* __restrict__ col,
                                   const float* __restrict__ X, const float* __restrict__ s,
                                   const float* __restrict__ t, float* __restrict__ out, int n) {
    int tid = threadIdx.x;
    int node = blockIdx.x * 4 + (tid >> 6);
    int f4 = tid & 63;
    if (node >= n) return;
    float tv = t[node];
    if (MASKED && tv == 0.f) return;
    int e0 = row_ptr[node], e1 = row_ptr[node + 1];
    const float4* X4 = (const float4*)X;
    float ax = 0.f, ay = 0.f, az = 0.f, aw = 0.f;
    int e = e0;
    for (; e + 3 < e1; e += 4) {
        int u0 = col[e], u1 = col[e + 1], u2 = col[e + 2], u3 = col[e + 3];
        float s0 = s[u0], s1 = s[u1], s2 = s[u2], s3 = s[u3];
        if (!MASKED) {
            float4 x0 = X4[(size_t)u0 * 64 + f4];
            float4 x1 = X4[(size_t)u1 * 64 + f4];
            float4 x2 = X4[(size_t)u2 * 64 + f4];
            float4 x3 = X4[(size_t)u3 * 64 + f4];
            ax += s0 * x0.x; ay += s0 * x0.y; az += s0 * x0.z; aw += s0 * x0.w;
            ax += s1 * x1.x; ay += s1 * x1.y; az += s1 * x1.z; aw += s1 * x1.w;
            ax += s2 * x2.x; ay += s2 * x2.y; az += s2 * x2.z; aw += s2 * x2.w;
            ax += s3 * x3.x; ay += s3 * x3.y; az += s3 * x3.z; aw += s3 * x3.w;
        } else {
            if (s0 != 0.f) { float4 x = X4[(size_t)u0 * 64 + f4];
                ax += s0 * x.x; ay += s0 * x.y; az += s0 * x.z; aw += s0 * x.w; }
            if (s1 != 0.f) { float4 x = X4[(size_t)u1 * 64 + f4];
                ax += s1 * x.x; ay += s1 * x.y; az += s1 * x.z; aw += s1 * x.w; }
            if (s2 != 0.f) { float4 x = X4[(size_t)u2 * 64 + f4];
                ax += s2 * x.x; ay += s2 * x.y; az += s2 * x.z; aw += s2 * x.w; }
            if (s3 != 0.f) { float4 x = X4[(size_t)u3 * 64 + f4];
                ax += s3 * x.x; ay += s3 * x.y; az += s3 * x.z; aw += s3 * x.w; }
        }
    }
    for (; e < e1; ++e) {
        int u = col[e];
        float sc = s[u];
        if (!MASKED || sc != 0.f) {
            float4 xv = X4[(size_t)u * 64 + f4];
            ax += sc * xv.x; ay += sc * xv.y; az += sc * xv.z; aw += sc * xv.w;
        }
    }
    float4 r; r.x = ax * tv; r.y = ay * tv; r.z = az * tv; r.w = aw * tv;
    ((float4*)out)[(size_t)node * 64 + f4] = r;
}

// ---------------- GEMM: out[M,Nn] = act(A[M,K] @ W[K,Nn] + b) * mask ----------------
// R8 64x64 / 4x4 version (R9's 128x128 regressed; reverted).
template <bool RELU>
__global__ __launch_bounds__(256) void gemm_kernel(const float* __restrict__ A,
                                                   const float* __restrict__ W,
                                                   const float* __restrict__ bias,
                                                   const float* __restrict__ mask,
                                                   float* __restrict__ C, int M, int K, int Nn) {
    __shared__ float As[16][68];
    __shared__ float Bs[16][68];
    int tid = threadIdx.x;
    int bm = blockIdx.x * 64, bn = blockIdx.y * 64;
    int mA = tid >> 2, kqA = (tid & 3) * 4;
    int kB = tid >> 4, nqB = (tid & 15) * 4;
    int tn = (tid & 15) * 4, tm = (tid >> 4) * 4;
    float acc[4][4] = {};
    for (int k0 = 0; k0 < K; k0 += 16) {
        float4 av = *(const float4*)(A + (size_t)(bm + mA) * K + k0 + kqA);
        As[kqA + 0][mA] = av.x; As[kqA + 1][mA] = av.y;
        As[kqA + 2][mA] = av.z; As[kqA + 3][mA] = av.w;
        float4 bv = *(const float4*)(W + (size_t)(k0 + kB) * Nn + bn + nqB);
        *(float4*)&Bs[kB][nqB] = bv;
        __syncthreads();
        #pragma unroll
        for (int kk = 0; kk < 16; ++kk) {
            float4 a = *(const float4*)&As[kk][tm];
            float4 b = *(const float4*)&Bs[kk][tn];
            float ar[4] = {a.x, a.y, a.z, a.w};
            float br[4] = {b.x, b.y, b.z, b.w};
            #pragma unroll
            for (int i2 = 0; i2 < 4; i2++)
                #pragma unroll
                for (int j = 0; j < 4; j++) acc[i2][j] += ar[i2] * br[j];
        }
        __syncthreads();
    }
    #pragma unroll
    for (int i2 = 0; i2 < 4; i2++) {
        int row = bm + tm + i2;
        if (row < M) {
            float mv = mask ? mask[row] : 1.f;
            #pragma unroll
            for (int j = 0; j < 4; j++) {
                float x = acc[i2][j] + bias[bn + tn + j];
                if (RELU) x = fmaxf(x, 0.f);
                x *= mv;
                C[(size_t)row * Nn + bn + tn + j] = x;
            }
        }
    }
}

// ---------------- pooling score: sigmoid(h . wp + bp) ----------------
__global__ void score_kernel(const float* __restrict__ H, const float* __restrict__ Wp,
                             const float* __restrict__ bp, const float* __restrict__ mask,
                             float* __restrict__ scores, float* __restrict__ keys, int n) {
    int lane = threadIdx.x & 63;
    int node = blockIdx.x * 4 + (threadIdx.x >> 6);
    if (node >= n) return;
    float4 hv = ((const float4*)(H + (size_t)node * 256))[lane];
    float4 wq = ((const float4*)Wp)[lane];
    float d = hv.x * wq.x + hv.y * wq.y + hv.z * wq.z + hv.w * wq.w;
    #pragma unroll
    for (int off = 32; off > 0; off >>= 1) d += __shfl_down(d, off);
    if (lane == 0) {
        float sc = 1.f / (1.f + expf(-(d + bp[0])));
        scores[node] = sc;
        keys[node] = (mask && mask[node] == 0.f) ? -1e9f : sc;
    }
}

// ---------------- top-K selection ----------------
__device__ __forceinline__ unsigned key_u(float f) {
    unsigned u = __float_as_uint(f);
    return (u & 0x80000000u) ? ~u : (u | 0x80000000u);
}

// Wave-aggregated histogram increment (R7 win: clustered keys serialize naive
// atomics; leader adds popcount once per distinct bin per wave).
__device__ __forceinline__ void wave_hist_add(int* __restrict__ hist, unsigned bin, bool valid) {
    int lane = threadIdx.x & 63;
    while (true) {
        unsigned long long vmask = __ballot(valid);
        if (vmask == 0ull) break;
        int leader = __ffsll((long long)vmask) - 1;
        unsigned lbin = (unsigned)__shfl((int)bin, leader);
        bool match = valid && (bin == lbin);
        unsigned long long mmask = __ballot(match);
        if (lane == leader) atomicAdd(&hist[lbin], __popcll(mmask));
        if (match) valid = false;
    }
}

// -------- fallback: single block radix select (known-good R2/R5) --------
__global__ void topk_kernel(const float* __restrict__ keys, const float* __restrict__ scores,
                            float* __restrict__ nm, float* __restrict__ gate, int n, int K) {
    __shared__ int hist[256];
    __shared__ unsigned sh_prefix;
    __shared__ int sh_krem;
    __shared__ int sh_running;
    __shared__ int wsum[16];
    int tid = threadIdx.x, lane = tid & 63, wid = tid >> 6;
    if (tid == 0) { sh_prefix = 0u; sh_krem = K; sh_running = 0; }
    __syncthreads();
    for (int pass = 0; pass < 4; ++pass) {
        int shift = 24 - pass * 8;
        if (tid < 256) hist[tid] = 0;
        __syncthreads();
        unsigned pmask = (pass == 0) ? 0u : (0xFFFFFFFFu << (shift + 8));
        unsigned prefix = sh_prefix;
        for (int i = tid; i < n; i += 1024) {
            unsigned u = key_u(keys[i]);
            if ((u & pmask) == prefix) atomicAdd(&hist[(u >> shift) & 0xFF], 1);
        }
        __syncthreads();
        if (tid == 0) {
            int krem = sh_krem;
            int b;
            for (b = 255; b > 0; --b) {
                int c = hist[b];
                if (c >= krem) break;
                krem -= c;
            }
            sh_prefix = prefix | ((unsigned)b << shift);
            sh_krem = krem;
        }
        __syncthreads();
    }
    unsigned Tkey = sh_prefix;
    int need_eq = sh_krem;
    for (int base = 0; base < n; base += 1024) {
        int i = base + tid;
        unsigned u = 0; int flagv = 0;
        if (i < n) { u = key_u(keys[i]); flagv = (u == Tkey) ? 1 : 0; }
        unsigned long long bal = __ballot(flagv);
        int rank_w = __popcll(bal & ((1ull << lane) - 1ull));
        if (lane == 63) wsum[wid] = __popcll(bal);
        __syncthreads();
        int woff = 0;
        for (int w = 0; w < wid; ++w) woff += wsum[w];
        int grank = sh_running + woff + rank_w;
        if (i < n) {
            float v = (u > Tkey) ? 1.f : ((flagv && grank < need_eq) ? 1.f : 0.f);
            nm[i] = v;
            gate[i] = v * scores[i];
        }
        __syncthreads();
        if (tid == 0) {
            int tot = 0;
            for (int w = 0; w < 16; ++w) tot += wsum[w];
            sh_running += tot;
        }
        __syncthreads();
    }
}

// -------- fast path: grid-wide radix select, 2 passes of 16 bits --------
__global__ void topk_hist1(const float* __restrict__ keys, int n, int* __restrict__ hist) {
    int i = blockIdx.x * blockDim.x + threadIdx.x;
    unsigned bin = 0; bool valid = (i < n);
    if (valid) bin = key_u(keys[i]) >> 16;
    wave_hist_add(hist, bin, valid);
}

// single block (1024 thr): suffix-scan 64K bins; sel[0]=bucket, sel[1]=krem
__global__ void topk_scan1(const int* __restrict__ hist, int K, int* __restrict__ sel) {
    __shared__ int arr[1024];
    int tid = threadIdx.x;
    int base = tid * 64;
    int local = 0;
    #pragma unroll 8
    for (int b = 0; b < 64; ++b) local += hist[base + b];
    arr[tid] = local;
    __syncthreads();
    for (int off = 1; off < 1024; off <<= 1) {
        int v = (tid + off < 1024) ? arr[tid + off] : 0;
        __syncthreads();
        arr[tid] += v;
        __syncthreads();
    }
    int above = arr[tid] - local;       // suffix(tid+1)
    if (above < K && arr[tid] >= K) {   // unique: arr strictly decreasing in tid
        int run = above;
        for (int b = base + 63; b >= base; --b) {
            int c = hist[b];
            if (run + c >= K) { sel[0] = b; sel[1] = K - run; break; }
            run += c;
        }
    }
}

__global__ void topk_hist2(const float* __restrict__ keys, int n, const int* __restrict__ sel,
                           int* __restrict__ hist) {
    int i = blockIdx.x * blockDim.x + threadIdx.x;
    unsigned bin = 0; bool valid = false;
    if (i < n) {
        unsigned u = key_u(keys[i]);
        if ((int)(u >> 16) == sel[0]) { bin = u & 0xFFFF; valid = true; }
    }
    wave_hist_add(hist, bin, valid);
}

// single block: sel[2]=Tkey, sel[3]=need_eq; resets tie counter
__global__ void topk_scan2(const int* __restrict__ hist, int* __restrict__ sel,
                           int* __restrict__ tie_cnt) {
    __shared__ int arr[1024];
    int tid = threadIdx.x;
    if (tid == 0) *tie_cnt = 0;
    int K = sel[1];
    int base = tid * 64;
    int local = 0;
    #pragma unroll 8
    for (int b = 0; b < 64; ++b) local += hist[base + b];
    arr[tid] = local;
    __syncthreads();
    for (int off = 1; off < 1024; off <<= 1) {
        int v = (tid + off < 1024) ? arr[tid + off] : 0;
        __syncthreads();
        arr[tid] += v;
        __syncthreads();
    }
    int above = arr[tid] - local;
    if (above < K && arr[tid] >= K) {
        int run = above;
        for (int b = base + 63; b >= base; --b) {
            int c = hist[b];
            if (run + c >= K) {
                sel[2] = (int)((((unsigned)sel[0]) << 16) | (unsigned)b);
                sel[3] = K - run;
                break;
            }
            run += c;
        }
    }
}

// grid-wide mark: strictly-above selected; equal-to-threshold -> tie list
__global__ void topk_mark(const float* __restrict__ keys, const float* __restrict__ scores,
                          const int* __restrict__ sel, float* __restrict__ nm,
                          float* __restrict__ gate, int* __restrict__ tie_list,
                          int* __restrict__ tie_cnt, int n) {
    int i = blockIdx.x * blockDim.x + threadIdx.x;
    if (i >= n) return;
    unsigned Tkey = (unsigned)sel[2];
    unsigned u = key_u(keys[i]);
    float v = 0.f;
    if (u > Tkey) v = 1.f;
    else if (u == Tkey) { int p = atomicAdd(tie_cnt, 1); tie_list[p] = i; }
    nm[i] = v;
    gate[i] = v * scores[i];
}

// single block: ties resolved lowest-index-first (rank by index value ->
// independent of nondeterministic tie_list order)
__global__ void topk_ties(const float* __restrict__ scores, const int* __restrict__ sel,
                          const int* __restrict__ tie_list, const int* __restrict__ tie_cnt,
                          float* __restrict__ nm, float* __restrict__ gate) {
    int cnt = *tie_cnt;
    int need = sel[3];
    for (int j = threadIdx.x; j < cnt; j += blockDim.x) {
        int idx = tie_list[j];
        int rank = 0;
        for (int k2 = 0; k2 < cnt; ++k2) rank += (tie_list[k2] < idx) ? 1 : 0;
        if (rank < need) { nm[idx] = 1.f; gate[idx] = scores[idx]; }
    }
}

// ---------------- elementwise add: A += B ----------------
__global__ void add_kernel(float* __restrict__ A, const float* __restrict__ B, int n4) {
    int i = blockIdx.x * blockDim.x + threadIdx.x;
    if (i < n4) {
        float4 a = ((float4*)A)[i];
        float4 b = ((const float4*)B)[i];
        a.x += b.x; a.y += b.y; a.z += b.z; a.w += b.w;
        ((float4*)A)[i] = a;
    }
}

extern "C" void kernel_launch(void* const* d_in, const int* in_sizes, int n_in,
                              void* d_out, int out_size, void* d_ws, size_t ws_size,
                              hipStream_t stream) {
    const int n = in_sizes[0] / 128;   // 50000
    const int E = in_sizes[1];         // 800000
    const int NPAD = ((n + 63) / 64) * 64;
    const int K1 = 25000, K2 = 12500;

    const float* features = (const float*)d_in[0];
    const int* src = (const int*)d_in[1];
    const int* dst = (const int*)d_in[2];
    const float* W_embed = (const float*)d_in[3];
    const float* b_embed = (const float*)d_in[4];
    const float* W_enc0  = (const float*)d_in[5];
    const float* b_enc0  = (const float*)d_in[6];
    const float* W_enc1  = (const float*)d_in[7];
    const float* b_enc1  = (const float*)d_in[8];
    const float* W_p0    = (const float*)d_in[9];
    const float* b_p0    = (const float*)d_in[10];
    const float* W_p1    = (const float*)d_in[11];
    const float* b_p1    = (const float*)d_in[12];
    const float* W_bot   = (const float*)d_in[13];
    const float* b_bot   = (const float*)d_in[14];
    const float* W_dec0  = (const float*)d_in[15];
    const float* b_dec0  = (const float*)d_in[16];
    const float* W_dec1  = (const float*)d_in[17];
    const float* b_dec1  = (const float*)d_in[18];
    float* out_f = (float*)d_out;

    char* ws = (char*)d_ws;
    size_t off = 0;
    auto alloc = [&](size_t bytes) -> void* {
        void* p = ws + off;
        off += (bytes + 255) & ~(size_t)255;
        return p;
    };
    (void)alloc(256);  // pad (R2 'flag' slot)
    int* row_ptr  = (int*)alloc((size_t)(n + 1) * 4);
    int* cursor   = (int*)alloc((size_t)n * 4);
    int* col      = (int*)alloc((size_t)E * 4);
    int* deg_out_i= (int*)alloc((size_t)n * 4);
    int* deg_in_i = (int*)alloc((size_t)n * 4);
    float* so_m1  = (float*)alloc((size_t)n * 4);
    float* si_m1  = (float*)alloc((size_t)n * 4);
    float* so_m2  = (float*)alloc((size_t)n * 4);
    float* si_m2  = (float*)alloc((size_t)n * 4);
    float* sarr   = (float*)alloc((size_t)n * 4);
    float* tarr   = (float*)alloc((size_t)n * 4);
    float* scores1= (float*)alloc((size_t)n * 4);
    float* keys1  = (float*)alloc((size_t)n * 4);
    float* scores2= (float*)alloc((size_t)n * 4);
    float* keys2  = (float*)alloc((size_t)n * 4);
    float* nm1    = (float*)alloc((size_t)n * 4);
    float* gate1  = (float*)alloc((size_t)n * 4);
    float* nm2    = (float*)alloc((size_t)n * 4);
    float* gate2  = (float*)alloc((size_t)n * 4);
    size_t big = (size_t)NPAD * 256 * 4;
    float* A = (float*)alloc(big);
    float* B = (float*)alloc(big);
    float* C = (float*)alloc(big);
    float* D = (float*)alloc(big);
    // ---- tail ----
    int* rhist    = (int*)alloc(65536 * 4);
    int* sel      = (int*)alloc(256);
    int* tie_cnt  = (int*)alloc(256);
    int* tie_list = (int*)alloc((size_t)n * 4);
    float* s0     = (float*)alloc((size_t)n * 4);
    float* t0     = (float*)alloc((size_t)n * 4);
    bool fast = (off <= ws_size);   // host-constant: same decision every call

    dim3 blk(256);
    int gE = (E + 255) / 256;
    int gN = (n + 255) / 256;
    int gAgg256 = (n + 3) / 4;
    int gAgg128 = (n + 7) / 8;
    int gScore = (n + 3) / 4;
    dim3 gemm_g(NPAD / 64, 4);
    dim3 gemm_g128(NPAD / 64, 2);
    int gAdd = (n * 64 + 255) / 256;

    auto run_topk = [&](const float* keys, const float* scores, float* nm, float* gate, int K) {
        if (fast) {
            hipMemsetAsync(rhist, 0, 65536 * 4, stream);
            topk_hist1<<<gN, blk, 0, stream>>>(keys, n, rhist);
            topk_scan1<<<1, 1024, 0, stream>>>(rhist, K, sel);
            hipMemsetAsync(rhist, 0, 65536 * 4, stream);
            topk_hist2<<<gN, blk, 0, stream>>>(keys, n, sel, rhist);
            topk_scan2<<<1, 1024, 0, stream>>>(rhist, sel, tie_cnt);
            topk_mark<<<gN, blk, 0, stream>>>(keys, scores, sel, nm, gate, tie_list, tie_cnt, n);
            topk_ties<<<1, 256, 0, stream>>>(scores, sel, tie_list, tie_cnt, nm, gate);
        } else {
            topk_kernel<<<1, 1024, 0, stream>>>(keys, scores, nm, gate, n, K);
        }
    };
    float* sF = fast ? s0 : sarr;
    float* tF = fast ? t0 : tarr;

    // ---- CSR build ----
    hipMemsetAsync(deg_out_i, 0, (size_t)n * 4, stream);
    hipMemsetAsync(deg_in_i, 0, (size_t)n * 4, stream);
    hist_kernel<<<gE, blk, 0, stream>>>(src, dst, deg_out_i, deg_in_i, E);
    scan_kernel<<<1, 1024, 0, stream>>>(deg_in_i, row_ptr, cursor, n);
    fill_kernel<<<gE, blk, 0, stream>>>(src, dst, cursor, col, E);
    sort_rows_kernel<<<gN, blk, 0, stream>>>(row_ptr, col, n);

    // ---- full-graph degree scales (once) ----
    scale_full_kernel<<<gN, blk, 0, stream>>>(deg_out_i, deg_in_i, sF, tF, n);

    // ---- embed GCN (full graph) -> A ----
    agg_feat_128_kernel<<<gAgg128, blk, 0, stream>>>(row_ptr, col, features, sF, tF, D, n);
    gemm_kernel<true><<<gemm_g, blk, 0, stream>>>(D, W_embed, b_embed, nullptr, A, n, 128, 256);

    // ---- enc0 (full graph); hidden0 = B ----
    agg_f32_256_kernel<false><<<gAgg256, blk, 0, stream>>>(row_ptr, col, A, sF, tF, D, n);
    gemm_kernel<true><<<gemm_g, blk, 0, stream>>>(D, W_enc0, b_enc0, nullptr, B, n, 256, 256);

    // ---- pool0 ----
    score_kernel<<<gScore, blk, 0, stream>>>(B, W_p0, b_p0, nullptr, scores1, keys1, n);
    run_topk(keys1, scores1, nm1, gate1, K1);

    // ---- enc1 (mask m1, gated input); hidden1 = C ----
    hipMemsetAsync(so_m1, 0, (size_t)n * 4, stream);
    out_deg_mask_kernel<<<gE, blk, 0, stream>>>(src, dst, nm1, so_m1, E);
    in_deg_mask_kernel<<<gN, blk, 0, stream>>>(row_ptr, col, nm1, si_m1, n);
    scale_mask_kernel<<<gN, blk, 0, stream>>>(gate1, nm1, so_m1, si_m1, sarr, tarr, n);
    agg_f32_256_kernel<true><<<gAgg256, blk, 0, stream>>>(row_ptr, col, B, sarr, tarr, D, n);
    gemm_kernel<true><<<gemm_g, blk, 0, stream>>>(D, W_enc1, b_enc1, nm1, C, n, 256, 256);

    // ---- pool1 ----
    score_kernel<<<gScore, blk, 0, stream>>>(C, W_p1, b_p1, nm1, scores2, keys2, n);
    run_topk(keys2, scores2, nm2, gate2, K2);

    // ---- bottleneck (mask m2, gated input) -> A ----
    hipMemsetAsync(so_m2, 0, (size_t)n * 4, stream);
    out_deg_mask_kernel<<<gE, blk, 0, stream>>>(src, dst, nm2, so_m2, E);
    in_deg_mask_kernel<<<gN, blk, 0, stream>>>(row_ptr, col, nm2, si_m2, n);
    scale_mask_kernel<<<gN, blk, 0, stream>>>(gate2, nm2, so_m2, si_m2, sarr, tarr, n);
    agg_f32_256_kernel<true><<<gAgg256, blk, 0, stream>>>(row_ptr, col, C, sarr, tarr, D, n);
    gemm_kernel<true><<<gemm_g, blk, 0, stream>>>(D, W_bot, b_bot, nm2, A, n, 256, 256);

    // ---- dec0: h = bot + hidden1, GCN mask m1 -> A ----
    add_kernel<<<gAdd, blk, 0, stream>>>(A, C, n * 64);
    scale_mask_kernel<<<gN, blk, 0, stream>>>(nm1, nm1, so_m1, si_m1, sarr, tarr, n);
    agg_f32_256_kernel<true><<<gAgg256, blk, 0, stream>>>(row_ptr, col, A, sarr, tarr, D, n);
    gemm_kernel<true><<<gemm_g, blk, 0, stream>>>(D, W_dec0, b_dec0, nm1, A, n, 256, 256);

    // ---- dec1: h = dec0 + hidden0, GCN full graph, no relu -> d_out (f32) ----
    add_kernel<<<gAdd, blk, 0, stream>>>(A, B, n * 64);
    if (!fast)
        scale_full_kernel<<<gN, blk, 0, stream>>>(deg_out_i, deg_in_i, sarr, tarr, n);
    agg_f32_256_kernel<false><<<gAgg256, blk, 0, stream>>>(row_ptr, col, A, sF, tF, D, n);
    gemm_kernel<false><<<gemm_g128, blk, 0, stream>>>(D, W_dec1, b_dec1, nullptr, out_f, n, 256, 128);

    (void)n_in; (void)out_size;
}

// Round 11
// 1434.139 us; speedup vs baseline: 1.1504x; 1.0503x over previous
//
#include <hip/hip_runtime.h>
#include <hip/hip_bf16.h>
#include <type_traits>

// ---------------- CSR build ----------------
__global__ void hist_kernel(const int* __restrict__ src, const int* __restrict__ dst,
                            int* __restrict__ deg_out, int* __restrict__ deg_in, int E) {
    int e = blockIdx.x * blockDim.x + threadIdx.x;
    if (e < E) {
        atomicAdd(&deg_out[src[e]], 1);
        atomicAdd(&deg_in[dst[e]], 1);
    }
}

// single-block exclusive scan of deg (n) -> row_ptr[n+1], cursor copy
__global__ void scan_kernel(const int* __restrict__ deg, int* __restrict__ row_ptr,
                            int* __restrict__ cursor, int n) {
    __shared__ int wsum[16];
    __shared__ int running;
    int tid = threadIdx.x, lane = tid & 63, wid = tid >> 6;
    if (tid == 0) running = 0;
    __syncthreads();
    for (int base = 0; base < n; base += 1024) {
        int i = base + tid;
        int v = (i < n) ? deg[i] : 0;
        int incl = v;
        #pragma unroll
        for (int off = 1; off < 64; off <<= 1) {
            int t = __shfl_up(incl, off);
            if (lane >= off) incl += t;
        }
        if (lane == 63) wsum[wid] = incl;
        __syncthreads();
        if (wid == 0 && lane < 16) {
            int s = wsum[lane], si = s;
            #pragma unroll
            for (int off = 1; off < 16; off <<= 1) {
                int t = __shfl_up(si, off);
                if (lane >= off) si += t;
            }
            wsum[lane] = si - s;  // exclusive
        }
        __syncthreads();
        int excl = running + wsum[wid] + (incl - v);
        if (i < n) { row_ptr[i] = excl; cursor[i] = excl; }
        __syncthreads();
        if (tid == 1023) running = excl + v;
        __syncthreads();
    }
    if (tid == 0) row_ptr[n] = running;
}

__global__ void fill_kernel(const int* __restrict__ src, const int* __restrict__ dst,
                            int* __restrict__ cursor, int* __restrict__ col, int E) {
    int e = blockIdx.x * blockDim.x + threadIdx.x;
    if (e < E) {
        int p = atomicAdd(&cursor[dst[e]], 1);
        col[p] = src[e];
    }
}

// deterministic neighbor order: insertion-sort each CSR row (avg deg 16)
__global__ void sort_rows_kernel(const int* __restrict__ row_ptr, int* __restrict__ col, int n) {
    int v = blockIdx.x * blockDim.x + threadIdx.x;
    if (v >= n) return;
    int e0 = row_ptr[v], e1 = row_ptr[v + 1];
    for (int i = e0 + 1; i < e1; ++i) {
        int key = col[i];
        int j = i - 1;
        while (j >= e0 && col[j] > key) { col[j + 1] = col[j]; --j; }
        col[j + 1] = key;
    }
}

// ---------------- masked degrees ----------------
__global__ void out_deg_mask_kernel(const int* __restrict__ src, const int* __restrict__ dst,
                                    const float* __restrict__ m, float* __restrict__ so, int E) {
    int e = blockIdx.x * blockDim.x + threadIdx.x;
    if (e < E) {
        float md = m[dst[e]];
        if (md != 0.f) atomicAdd(&so[src[e]], md);
    }
}

__global__ void in_deg_mask_kernel(const int* __restrict__ row_ptr, const int* __restrict__ col,
                                   const float* __restrict__ m, float* __restrict__ si, int n) {
    int v = blockIdx.x * blockDim.x + threadIdx.x;
    if (v < n) {
        float s = 0.f;
        int e1 = row_ptr[v + 1];
        for (int e = row_ptr[v]; e < e1; ++e) s += m[col[e]];
        si[v] = s;
    }
}

__global__ void scale_full_kernel(const int* __restrict__ dout, const int* __restrict__ din,
                                  float* __restrict__ s, float* __restrict__ t, int n) {
    int v = blockIdx.x * blockDim.x + threadIdx.x;
    if (v < n) {
        s[v] = 1.f / sqrtf((float)max(dout[v], 1));
        t[v] = 1.f / sqrtf((float)max(din[v], 1));
    }
}

__global__ void scale_mask_kernel(const float* __restrict__ gate, const float* __restrict__ mask,
                                  const float* __restrict__ so, const float* __restrict__ si,
                                  float* __restrict__ s, float* __restrict__ t, int n) {
    int v = blockIdx.x * blockDim.x + threadIdx.x;
    if (v < n) {
        s[v] = gate[v] * (1.f / sqrtf(fmaxf(so[v], 1.f)));
        t[v] = mask[v] * (1.f / sqrtf(fmaxf(si[v], 1.f)));
    }
}

// ---------------- aggregation from f32 FEATURES, F=128 (full graph: s never 0) ----------------
__global__ void agg_feat_128_kernel(const int* __restrict__ row_ptr, const int* __restrict__ col,
                                    const float* __restrict__ X, const float* __restrict__ s,
                                    const float* __restrict__ t, float* __restrict__ out, int n) {
    int tid = threadIdx.x;
    int node = blockIdx.x * 8 + (tid >> 5);
    int f4 = tid & 31;
    if (node >= n) return;
    int e0 = row_ptr[node], e1 = row_ptr[node + 1];
    const float4* X4 = (const float4*)X;
    float ax = 0.f, ay = 0.f, az = 0.f, aw = 0.f;
    int e = e0;
    for (; e + 3 < e1; e += 4) {
        int u0 = col[e], u1 = col[e + 1], u2 = col[e + 2], u3 = col[e + 3];
        float s0 = s[u0], s1 = s[u1], s2 = s[u2], s3 = s[u3];
        float4 x0 = X4[(size_t)u0 * 32 + f4];
        float4 x1 = X4[(size_t)u1 * 32 + f4];
        float4 x2 = X4[(size_t)u2 * 32 + f4];
        float4 x3 = X4[(size_t)u3 * 32 + f4];
        ax += s0 * x0.x; ay += s0 * x0.y; az += s0 * x0.z; aw += s0 * x0.w;
        ax += s1 * x1.x; ay += s1 * x1.y; az += s1 * x1.z; aw += s1 * x1.w;
        ax += s2 * x2.x; ay += s2 * x2.y; az += s2 * x2.z; aw += s2 * x2.w;
        ax += s3 * x3.x; ay += s3 * x3.y; az += s3 * x3.z; aw += s3 * x3.w;
    }
    for (; e < e1; ++e) {
        int u = col[e];
        float sc = s[u];
        float4 q = X4[(size_t)u * 32 + f4];
        ax += sc * q.x; ay += sc * q.y; az += sc * q.z; aw += sc * q.w;
    }
    float tv = t[node];
    float4 r; r.x = ax * tv; r.y = ay * tv; r.z = az * tv; r.w = aw * tv;
    ((float4*)out)[(size_t)node * 32 + f4] = r;
}

// ---------------- aggregation over f32 workspace, F=256 ----------------
// MASKED=false: no guards, 8x unroll (R11) -> 8 gathers in flight.
// MASKED=true: t==0 row skip + s!=0 guards, guarded 4x unroll.
// Both preserve e-order accumulation -> bit-identical.
template <bool MASKED>
__global__ void agg_f32_256_kernel(const int* __restrict__ row_ptr, const int* __restrict__ col,
                                   const float* __restrict__ X, const float* __restrict__ s,
                                   const float* __restrict__ t, float* __restrict__ out, int n) {
    int tid = threadIdx.x;
    int node = blockIdx.x * 4 + (tid >> 6);
    int f4 = tid & 63;
    if (node >= n) return;
    float tv = t[node];
    if (MASKED && tv == 0.f) return;
    int e0 = row_ptr[node], e1 = row_ptr[node + 1];
    const float4* X4 = (const float4*)X;
    float ax = 0.f, ay = 0.f, az = 0.f, aw = 0.f;
    int e = e0;
    if (!MASKED) {
        for (; e + 7 < e1; e += 8) {
            int u0 = col[e],     u1 = col[e + 1], u2 = col[e + 2], u3 = col[e + 3];
            int u4 = col[e + 4], u5 = col[e + 5], u6 = col[e + 6], u7 = col[e + 7];
            float s0 = s[u0], s1 = s[u1], s2 = s[u2], s3 = s[u3];
            float s4 = s[u4], s5 = s[u5], s6 = s[u6], s7 = s[u7];
            float4 x0 = X4[(size_t)u0 * 64 + f4];
            float4 x1 = X4[(size_t)u1 * 64 + f4];
            float4 x2 = X4[(size_t)u2 * 64 + f4];
            float4 x3 = X4[(size_t)u3 * 64 + f4];
            float4 x4v = X4[(size_t)u4 * 64 + f4];
            float4 x5 = X4[(size_t)u5 * 64 + f4];
            float4 x6 = X4[(size_t)u6 * 64 + f4];
            float4 x7 = X4[(size_t)u7 * 64 + f4];
            ax += s0 * x0.x;  ay += s0 * x0.y;  az += s0 * x0.z;  aw += s0 * x0.w;
            ax += s1 * x1.x;  ay += s1 * x1.y;  az += s1 * x1.z;  aw += s1 * x1.w;
            ax += s2 * x2.x;  ay += s2 * x2.y;  az += s2 * x2.z;  aw += s2 * x2.w;
            ax += s3 * x3.x;  ay += s3 * x3.y;  az += s3 * x3.z;  aw += s3 * x3.w;
            ax += s4 * x4v.x; ay += s4 * x4v.y; az += s4 * x4v.z; aw += s4 * x4v.w;
            ax += s5 * x5.x;  ay += s5 * x5.y;  az += s5 * x5.z;  aw += s5 * x5.w;
            ax += s6 * x6.x;  ay += s6 * x6.y;  az += s6 * x6.z;  aw += s6 * x6.w;
            ax += s7 * x7.x;  ay += s7 * x7.y;  az += s7 * x7.z;  aw += s7 * x7.w;
        }
    }
    for (; e + 3 < e1; e += 4) {
        int u0 = col[e], u1 = col[e + 1], u2 = col[e + 2], u3 = col[e + 3];
        float s0 = s[u0], s1 = s[u1], s2 = s[u2], s3 = s[u3];
        if (!MASKED) {
            float4 x0 = X4[(size_t)u0 * 64 + f4];
            float4 x1 = X4[(size_t)u1 * 64 + f4];
            float4 x2 = X4[(size_t)u2 * 64 + f4];
            float4 x3 = X4[(size_t)u3 * 64 + f4];
            ax += s0 * x0.x; ay += s0 * x0.y; az += s0 * x0.z; aw += s0 * x0.w;
            ax += s1 * x1.x; ay += s1 * x1.y; az += s1 * x1.z; aw += s1 * x1.w;
            ax += s2 * x2.x; ay += s2 * x2.y; az += s2 * x2.z; aw += s2 * x2.w;
            ax += s3 * x3.x; ay += s3 * x3.y; az += s3 * x3.z; aw += s3 * x3.w;
        } else {
            if (s0 != 0.f) { float4 x = X4[(size_t)u0 * 64 + f4];
                ax += s0 * x.x; ay += s0 * x.y; az += s0 * x.z; aw += s0 * x.w; }
            if (s1 != 0.f) { float4 x = X4[(size_t)u1 * 64 + f4];
                ax += s1 * x.x; ay += s1 * x.y; az += s1 * x.z; aw += s1 * x.w; }
            if (s2 != 0.f) { float4 x = X4[(size_t)u2 * 64 + f4];
                ax += s2 * x.x; ay += s2 * x.y; az += s2 * x.z; aw += s2 * x.w; }
            if (s3 != 0.f) { float4 x = X4[(size_t)u3 * 64 + f4];
                ax += s3 * x.x; ay += s3 * x.y; az += s3 * x.z; aw += s3 * x.w; }
        }
    }
    for (; e < e1; ++e) {
        int u = col[e];
        float sc = s[u];
        if (!MASKED || sc != 0.f) {
            float4 xv = X4[(size_t)u * 64 + f4];
            ax += sc * xv.x; ay += sc * xv.y; az += sc * xv.z; aw += sc * xv.w;
        }
    }
    float4 r; r.x = ax * tv; r.y = ay * tv; r.z = az * tv; r.w = aw * tv;
    ((float4*)out)[(size_t)node * 64 + f4] = r;
}

// ---------------- post-GEMM 128-dim gather for dec1 (R11 reorder) ----------------
// out_v = t[v] * sum_{u in N(v)} P[u] + bias   (P already row-scaled by s)
__global__ void agg_bias_128_kernel(const int* __restrict__ row_ptr, const int* __restrict__ col,
                                    const float* __restrict__ P, const float* __restrict__ t,
                                    const float* __restrict__ bias, float* __restrict__ out, int n) {
    int tid = threadIdx.x;
    int node = blockIdx.x * 8 + (tid >> 5);
    int f4 = tid & 31;
    if (node >= n) return;
    int e0 = row_ptr[node], e1 = row_ptr[node + 1];
    const float4* P4 = (const float4*)P;
    float ax = 0.f, ay = 0.f, az = 0.f, aw = 0.f;
    int e = e0;
    for (; e + 3 < e1; e += 4) {
        int u0 = col[e], u1 = col[e + 1], u2 = col[e + 2], u3 = col[e + 3];
        float4 x0 = P4[(size_t)u0 * 32 + f4];
        float4 x1 = P4[(size_t)u1 * 32 + f4];
        float4 x2 = P4[(size_t)u2 * 32 + f4];
        float4 x3 = P4[(size_t)u3 * 32 + f4];
        ax += x0.x; ay += x0.y; az += x0.z; aw += x0.w;
        ax += x1.x; ay += x1.y; az += x1.z; aw += x1.w;
        ax += x2.x; ay += x2.y; az += x2.z; aw += x2.w;
        ax += x3.x; ay += x3.y; az += x3.z; aw += x3.w;
    }
    for (; e < e1; ++e) {
        int u = col[e];
        float4 q = P4[(size_t)u * 32 + f4];
        ax += q.x; ay += q.y; az += q.z; aw += q.w;
    }
    float tv = t[node];
    float4 bv = ((const float4*)bias)[f4];
    float4 r;
    r.x = ax * tv + bv.x; r.y = ay * tv + bv.y;
    r.z = az * tv + bv.z; r.w = aw * tv + bv.w;
    ((float4*)out)[(size_t)node * 32 + f4] = r;
}

// ---------------- GEMM: out[M,Nn] = act(A[M,K] @ W[K,Nn] + b) * mask ----------------
// R8 64x64 / 4x4 (proven). rowscale (nullable) multiplies A rows on stage-in
// (used by dec1 reorder); bias nullable (treated as 0).
template <bool RELU>
__global__ __launch_bounds__(256) void gemm_kernel(const float* __restrict__ A,
                                                   const float* __restrict__ W,
                                                   const float* __restrict__ bias,
                                                   const float* __restrict__ mask,
                                                   const float* __restrict__ rowscale,
                                                   float* __restrict__ C, int M, int K, int Nn) {
    __shared__ float As[16][68];
    __shared__ float Bs[16][68];
    int tid = threadIdx.x;
    int bm = blockIdx.x * 64, bn = blockIdx.y * 64;
    int mA = tid >> 2, kqA = (tid & 3) * 4;
    int kB = tid >> 4, nqB = (tid & 15) * 4;
    int tn = (tid & 15) * 4, tm = (tid >> 4) * 4;
    float acc[4][4] = {};
    float rs = rowscale ? rowscale[bm + mA] : 1.f;
    for (int k0 = 0; k0 < K; k0 += 16) {
        float4 av = *(const float4*)(A + (size_t)(bm + mA) * K + k0 + kqA);
        As[kqA + 0][mA] = av.x * rs; As[kqA + 1][mA] = av.y * rs;
        As[kqA + 2][mA] = av.z * rs; As[kqA + 3][mA] = av.w * rs;
        float4 bv = *(const float4*)(W + (size_t)(k0 + kB) * Nn + bn + nqB);
        *(float4*)&Bs[kB][nqB] = bv;
        __syncthreads();
        #pragma unroll
        for (int kk = 0; kk < 16; ++kk) {
            float4 a = *(const float4*)&As[kk][tm];
            float4 b = *(const float4*)&Bs[kk][tn];
            float ar[4] = {a.x, a.y, a.z, a.w};
            float br[4] = {b.x, b.y, b.z, b.w};
            #pragma unroll
            for (int i2 = 0; i2 < 4; i2++)
                #pragma unroll
                for (int j = 0; j < 4; j++) acc[i2][j] += ar[i2] * br[j];
        }
        __syncthreads();
    }
    #pragma unroll
    for (int i2 = 0; i2 < 4; i2++) {
        int row = bm + tm + i2;
        if (row < M) {
            float mv = mask ? mask[row] : 1.f;
            #pragma unroll
            for (int j = 0; j < 4; j++) {
                float x = acc[i2][j] + (bias ? bias[bn + tn + j] : 0.f);
                if (RELU) x = fmaxf(x, 0.f);
                x *= mv;
                C[(size_t)row * Nn + bn + tn + j] = x;
            }
        }
    }
}

// ---------------- pooling score: sigmoid(h . wp + bp) ----------------
__global__ void score_kernel(const float* __restrict__ H, const float* __restrict__ Wp,
                             const float* __restrict__ bp, const float* __restrict__ mask,
                             float* __restrict__ scores, float* __restrict__ keys, int n) {
    int lane = threadIdx.x & 63;
    int node = blockIdx.x * 4 + (threadIdx.x >> 6);
    if (node >= n) return;
    float4 hv = ((const float4*)(H + (size_t)node * 256))[lane];
    float4 wq = ((const float4*)Wp)[lane];
    float d = hv.x * wq.x + hv.y * wq.y + hv.z * wq.z + hv.w * wq.w;
    #pragma unroll
    for (int off = 32; off > 0; off >>= 1) d += __shfl_down(d, off);
    if (lane == 0) {
        float sc = 1.f / (1.f + expf(-(d + bp[0])));
        scores[node] = sc;
        keys[node] = (mask && mask[node] == 0.f) ? -1e9f : sc;
    }
}

// ---------------- top-K selection ----------------
__device__ __forceinline__ unsigned key_u(float f) {
    unsigned u = __float_as_uint(f);
    return (u & 0x80000000u) ? ~u : (u | 0x80000000u);
}

// Wave-aggregated histogram increment (R7 win: clustered keys serialize naive
// atomics; leader adds popcount once per distinct bin per wave).
__device__ __forceinline__ void wave_hist_add(int* __restrict__ hist, unsigned bin, bool valid) {
    int lane = threadIdx.x & 63;
    while (true) {
        unsigned long long vmask = __ballot(valid);
        if (vmask == 0ull) break;
        int leader = __ffsll((long long)vmask) - 1;
        unsigned lbin = (unsigned)__shfl((int)bin, leader);
        bool match = valid && (bin == lbin);
        unsigned long long mmask = __ballot(match);
        if (lane == leader) atomicAdd(&hist[lbin], __popcll(mmask));
        if (match) valid = false;
    }
}

// -------- fallback: single block radix select (known-good R2/R5) --------
__global__ void topk_kernel(const float* __restrict__ keys, const float* __restrict__ scores,
                            float* __restrict__ nm, float* __restrict__ gate, int n, int K) {
    __shared__ int hist[256];
    __shared__ unsigned sh_prefix;
    __shared__ int sh_krem;
    __shared__ int sh_running;
    __shared__ int wsum[16];
    int tid = threadIdx.x, lane = tid & 63, wid = tid >> 6;
    if (tid == 0) { sh_prefix = 0u; sh_krem = K; sh_running = 0; }
    __syncthreads();
    for (int pass = 0; pass < 4; ++pass) {
        int shift = 24 - pass * 8;
        if (tid < 256) hist[tid] = 0;
        __syncthreads();
        unsigned pmask = (pass == 0) ? 0u : (0xFFFFFFFFu << (shift + 8));
        unsigned prefix = sh_prefix;
        for (int i = tid; i < n; i += 1024) {
            unsigned u = key_u(keys[i]);
            if ((u & pmask) == prefix) atomicAdd(&hist[(u >> shift) & 0xFF], 1);
        }
        __syncthreads();
        if (tid == 0) {
            int krem = sh_krem;
            int b;
            for (b = 255; b > 0; --b) {
                int c = hist[b];
                if (c >= krem) break;
                krem -= c;
            }
            sh_prefix = prefix | ((unsigned)b << shift);
            sh_krem = krem;
        }
        __syncthreads();
    }
    unsigned Tkey = sh_prefix;
    int need_eq = sh_krem;
    for (int base = 0; base < n; base += 1024) {
        int i = base + tid;
        unsigned u = 0; int flagv = 0;
        if (i < n) { u = key_u(keys[i]); flagv = (u == Tkey) ? 1 : 0; }
        unsigned long long bal = __ballot(flagv);
        int rank_w = __popcll(bal & ((1ull << lane) - 1ull));
        if (lane == 63) wsum[wid] = __popcll(bal);
        __syncthreads();
        int woff = 0;
        for (int w = 0; w < wid; ++w) woff += wsum[w];
        int grank = sh_running + woff + rank_w;
        if (i < n) {
            float v = (u > Tkey) ? 1.f : ((flagv && grank < need_eq) ? 1.f : 0.f);
            nm[i] = v;
            gate[i] = v * scores[i];
        }
        __syncthreads();
        if (tid == 0) {
            int tot = 0;
            for (int w = 0; w < 16; ++w) tot += wsum[w];
            sh_running += tot;
        }
        __syncthreads();
    }
}

// -------- fast path: grid-wide radix select, 2 passes of 16 bits --------
__global__ void topk_hist1(const float* __restrict__ keys, int n, int* __restrict__ hist) {
    int i = blockIdx.x * blockDim.x + threadIdx.x;
    unsigned bin = 0; bool valid = (i < n);
    if (valid) bin = key_u(keys[i]) >> 16;
    wave_hist_add(hist, bin, valid);
}

// single block (1024 thr): suffix-scan 64K bins; sel[0]=bucket, sel[1]=krem
__global__ void topk_scan1(const int* __restrict__ hist, int K, int* __restrict__ sel) {
    __shared__ int arr[1024];
    int tid = threadIdx.x;
    int base = tid * 64;
    int local = 0;
    #pragma unroll 8
    for (int b = 0; b < 64; ++b) local += hist[base + b];
    arr[tid] = local;
    __syncthreads();
    for (int off = 1; off < 1024; off <<= 1) {
        int v = (tid + off < 1024) ? arr[tid + off] : 0;
        __syncthreads();
        arr[tid] += v;
        __syncthreads();
    }
    int above = arr[tid] - local;       // suffix(tid+1)
    if (above < K && arr[tid] >= K) {   // unique: arr strictly decreasing in tid
        int run = above;
        for (int b = base + 63; b >= base; --b) {
            int c = hist[b];
            if (run + c >= K) { sel[0] = b; sel[1] = K - run; break; }
            run += c;
        }
    }
}

__global__ void topk_hist2(const float* __restrict__ keys, int n, const int* __restrict__ sel,
                           int* __restrict__ hist) {
    int i = blockIdx.x * blockDim.x + threadIdx.x;
    unsigned bin = 0; bool valid = false;
    if (i < n) {
        unsigned u = key_u(keys[i]);
        if ((int)(u >> 16) == sel[0]) { bin = u & 0xFFFF; valid = true; }
    }
    wave_hist_add(hist, bin, valid);
}

// single block: sel[2]=Tkey, sel[3]=need_eq; resets tie counter
__global__ void topk_scan2(const int* __restrict__ hist, int* __restrict__ sel,
                           int* __restrict__ tie_cnt) {
    __shared__ int arr[1024];
    int tid = threadIdx.x;
    if (tid == 0) *tie_cnt = 0;
    int K = sel[1];
    int base = tid * 64;
    int local = 0;
    #pragma unroll 8
    for (int b = 0; b < 64; ++b) local += hist[base + b];
    arr[tid] = local;
    __syncthreads();
    for (int off = 1; off < 1024; off <<= 1) {
        int v = (tid + off < 1024) ? arr[tid + off] : 0;
        __syncthreads();
        arr[tid] += v;
        __syncthreads();
    }
    int above = arr[tid] - local;
    if (above < K && arr[tid] >= K) {
        int run = above;
        for (int b = base + 63; b >= base; --b) {
            int c = hist[b];
            if (run + c >= K) {
                sel[2] = (int)((((unsigned)sel[0]) << 16) | (unsigned)b);
                sel[3] = K - run;
                break;
            }
            run += c;
        }
    }
}

// grid-wide mark: strictly-above selected; equal-to-threshold -> tie list
__global__ void topk_mark(const float* __restrict__ keys, const float* __restrict__ scores,
                          const int* __restrict__ sel, float* __restrict__ nm,
                          float* __restrict__ gate, int* __restrict__ tie_list,
                          int* __restrict__ tie_cnt, int n) {
    int i = blockIdx.x * blockDim.x + threadIdx.x;
    if (i >= n) return;
    unsigned Tkey = (unsigned)sel[2];
    unsigned u = key_u(keys[i]);
    float v = 0.f;
    if (u > Tkey) v = 1.f;
    else if (u == Tkey) { int p = atomicAdd(tie_cnt, 1); tie_list[p] = i; }
    nm[i] = v;
    gate[i] = v * scores[i];
}

// single block: ties resolved lowest-index-first (rank by index value ->
// independent of nondeterministic tie_list order)
__global__ void topk_ties(const float* __restrict__ scores, const int* __restrict__ sel,
                          const int* __restrict__ tie_list, const int* __restrict__ tie_cnt,
                          float* __restrict__ nm, float* __restrict__ gate) {
    int cnt = *tie_cnt;
    int need = sel[3];
    for (int j = threadIdx.x; j < cnt; j += blockDim.x) {
        int idx = tie_list[j];
        int rank = 0;
        for (int k2 = 0; k2 < cnt; ++k2) rank += (tie_list[k2] < idx) ? 1 : 0;
        if (rank < need) { nm[idx] = 1.f; gate[idx] = scores[idx]; }
    }
}

// ---------------- elementwise add: A += B ----------------
__global__ void add_kernel(float* __restrict__ A, const float* __restrict__ B, int n4) {
    int i = blockIdx.x * blockDim.x + threadIdx.x;
    if (i < n4) {
        float4 a = ((float4*)A)[i];
        float4 b = ((const float4*)B)[i];
        a.x += b.x; a.y += b.y; a.z += b.z; a.w += b.w;
        ((float4*)A)[i] = a;
    }
}

extern "C" void kernel_launch(void* const* d_in, const int* in_sizes, int n_in,
                              void* d_out, int out_size, void* d_ws, size_t ws_size,
                              hipStream_t stream) {
    const int n = in_sizes[0] / 128;   // 50000
    const int E = in_sizes[1];         // 800000
    const int NPAD = ((n + 63) / 64) * 64;
    const int K1 = 25000, K2 = 12500;

    const float* features = (const float*)d_in[0];
    const int* src = (const int*)d_in[1];
    const int* dst = (const int*)d_in[2];
    const float* W_embed = (const float*)d_in[3];
    const float* b_embed = (const float*)d_in[4];
    const float* W_enc0  = (const float*)d_in[5];
    const float* b_enc0  = (const float*)d_in[6];
    const float* W_enc1  = (const float*)d_in[7];
    const float* b_enc1  = (const float*)d_in[8];
    const float* W_p0    = (const float*)d_in[9];
    const float* b_p0    = (const float*)d_in[10];
    const float* W_p1    = (const float*)d_in[11];
    const float* b_p1    = (const float*)d_in[12];
    const float* W_bot   = (const float*)d_in[13];
    const float* b_bot   = (const float*)d_in[14];
    const float* W_dec0  = (const float*)d_in[15];
    const float* b_dec0  = (const float*)d_in[16];
    const float* W_dec1  = (const float*)d_in[17];
    const float* b_dec1  = (const float*)d_in[18];
    float* out_f = (float*)d_out;

    char* ws = (char*)d_ws;
    size_t off = 0;
    auto alloc = [&](size_t bytes) -> void* {
        void* p = ws + off;
        off += (bytes + 255) & ~(size_t)255;
        return p;
    };
    (void)alloc(256);  // pad (R2 'flag' slot)
    int* row_ptr  = (int*)alloc((size_t)(n + 1) * 4);
    int* cursor   = (int*)alloc((size_t)n * 4);
    int* col      = (int*)alloc((size_t)E * 4);
    int* deg_out_i= (int*)alloc((size_t)n * 4);
    int* deg_in_i = (int*)alloc((size_t)n * 4);
    float* so_m1  = (float*)alloc((size_t)n * 4);
    float* si_m1  = (float*)alloc((size_t)n * 4);
    float* so_m2  = (float*)alloc((size_t)n * 4);
    float* si_m2  = (float*)alloc((size_t)n * 4);
    float* sarr   = (float*)alloc((size_t)n * 4);
    float* tarr   = (float*)alloc((size_t)n * 4);
    float* scores1= (float*)alloc((size_t)n * 4);
    float* keys1  = (float*)alloc((size_t)n * 4);
    float* scores2= (float*)alloc((size_t)n * 4);
    float* keys2  = (float*)alloc((size_t)n * 4);
    float* nm1    = (float*)alloc((size_t)n * 4);
    float* gate1  = (float*)alloc((size_t)n * 4);
    float* nm2    = (float*)alloc((size_t)n * 4);
    float* gate2  = (float*)alloc((size_t)n * 4);
    size_t big = (size_t)NPAD * 256 * 4;
    float* A = (float*)alloc(big);
    float* B = (float*)alloc(big);
    float* C = (float*)alloc(big);
    float* D = (float*)alloc(big);
    // ---- tail ----
    int* rhist    = (int*)alloc(65536 * 4);
    int* sel      = (int*)alloc(256);
    int* tie_cnt  = (int*)alloc(256);
    int* tie_list = (int*)alloc((size_t)n * 4);
    float* s0     = (float*)alloc((size_t)n * 4);
    float* t0     = (float*)alloc((size_t)n * 4);
    bool fast = (off <= ws_size);   // host-constant: same decision every call

    dim3 blk(256);
    int gE = (E + 255) / 256;
    int gN = (n + 255) / 256;
    int gAgg256 = (n + 3) / 4;
    int gAgg128 = (n + 7) / 8;
    int gScore = (n + 3) / 4;
    dim3 gemm_g(NPAD / 64, 4);
    dim3 gemm_g128(NPAD / 64, 2);
    int gAdd = (n * 64 + 255) / 256;

    auto run_topk = [&](const float* keys, const float* scores, float* nm, float* gate, int K) {
        if (fast) {
            hipMemsetAsync(rhist, 0, 65536 * 4, stream);
            topk_hist1<<<gN, blk, 0, stream>>>(keys, n, rhist);
            topk_scan1<<<1, 1024, 0, stream>>>(rhist, K, sel);
            hipMemsetAsync(rhist, 0, 65536 * 4, stream);
            topk_hist2<<<gN, blk, 0, stream>>>(keys, n, sel, rhist);
            topk_scan2<<<1, 1024, 0, stream>>>(rhist, sel, tie_cnt);
            topk_mark<<<gN, blk, 0, stream>>>(keys, scores, sel, nm, gate, tie_list, tie_cnt, n);
            topk_ties<<<1, 256, 0, stream>>>(scores, sel, tie_list, tie_cnt, nm, gate);
        } else {
            topk_kernel<<<1, 1024, 0, stream>>>(keys, scores, nm, gate, n, K);
        }
    };
    float* sF = fast ? s0 : sarr;
    float* tF = fast ? t0 : tarr;

    // ---- CSR build ----
    hipMemsetAsync(deg_out_i, 0, (size_t)n * 4, stream);
    hipMemsetAsync(deg_in_i, 0, (size_t)n * 4, stream);
    hist_kernel<<<gE, blk, 0, stream>>>(src, dst, deg_out_i, deg_in_i, E);
    scan_kernel<<<1, 1024, 0, stream>>>(deg_in_i, row_ptr, cursor, n);
    fill_kernel<<<gE, blk, 0, stream>>>(src, dst, cursor, col, E);
    sort_rows_kernel<<<gN, blk, 0, stream>>>(row_ptr, col, n);

    // ---- full-graph degree scales (once) ----
    scale_full_kernel<<<gN, blk, 0, stream>>>(deg_out_i, deg_in_i, sF, tF, n);

    // ---- embed GCN (full graph) -> A ----
    agg_feat_128_kernel<<<gAgg128, blk, 0, stream>>>(row_ptr, col, features, sF, tF, D, n);
    gemm_kernel<true><<<gemm_g, blk, 0, stream>>>(D, W_embed, b_embed, nullptr, nullptr, A, n, 128, 256);

    // ---- enc0 (full graph); hidden0 = B ----
    agg_f32_256_kernel<false><<<gAgg256, blk, 0, stream>>>(row_ptr, col, A, sF, tF, D, n);
    gemm_kernel<true><<<gemm_g, blk, 0, stream>>>(D, W_enc0, b_enc0, nullptr, nullptr, B, n, 256, 256);

    // ---- pool0 ----
    score_kernel<<<gScore, blk, 0, stream>>>(B, W_p0, b_p0, nullptr, scores1, keys1, n);
    run_topk(keys1, scores1, nm1, gate1, K1);

    // ---- enc1 (mask m1, gated input); hidden1 = C ----
    hipMemsetAsync(so_m1, 0, (size_t)n * 4, stream);
    out_deg_mask_kernel<<<gE, blk, 0, stream>>>(src, dst, nm1, so_m1, E);
    in_deg_mask_kernel<<<gN, blk, 0, stream>>>(row_ptr, col, nm1, si_m1, n);
    scale_mask_kernel<<<gN, blk, 0, stream>>>(gate1, nm1, so_m1, si_m1, sarr, tarr, n);
    agg_f32_256_kernel<true><<<gAgg256, blk, 0, stream>>>(row_ptr, col, B, sarr, tarr, D, n);
    gemm_kernel<true><<<gemm_g, blk, 0, stream>>>(D, W_enc1, b_enc1, nm1, nullptr, C, n, 256, 256);

    // ---- pool1 ----
    score_kernel<<<gScore, blk, 0, stream>>>(C, W_p1, b_p1, nm1, scores2, keys2, n);
    run_topk(keys2, scores2, nm2, gate2, K2);

    // ---- bottleneck (mask m2, gated input) -> A ----
    hipMemsetAsync(so_m2, 0, (size_t)n * 4, stream);
    out_deg_mask_kernel<<<gE, blk, 0, stream>>>(src, dst, nm2, so_m2, E);
    in_deg_mask_kernel<<<gN, blk, 0, stream>>>(row_ptr, col, nm2, si_m2, n);
    scale_mask_kernel<<<gN, blk, 0, stream>>>(gate2, nm2, so_m2, si_m2, sarr, tarr, n);
    agg_f32_256_kernel<true><<<gAgg256, blk, 0, stream>>>(row_ptr, col, C, sarr, tarr, D, n);
    gemm_kernel<true><<<gemm_g, blk, 0, stream>>>(D, W_bot, b_bot, nm2, nullptr, A, n, 256, 256);

    // ---- dec0: h = bot + hidden1, GCN mask m1 -> A ----
    add_kernel<<<gAdd, blk, 0, stream>>>(A, C, n * 64);
    scale_mask_kernel<<<gN, blk, 0, stream>>>(nm1, nm1, so_m1, si_m1, sarr, tarr, n);
    agg_f32_256_kernel<true><<<gAgg256, blk, 0, stream>>>(row_ptr, col, A, sarr, tarr, D, n);
    gemm_kernel<true><<<gemm_g, blk, 0, stream>>>(D, W_dec0, b_dec0, nm1, nullptr, A, n, 256, 256);

    // ---- dec1 (R11 reorder, final layer): h = dec0 + hidden0;
    //      P = (s0 .* h) @ W_dec1  (no bias, no relu)  -> C
    //      out_v = t0[v] * sum_{u in N(v)} P[u] + b_dec1
    //      Associativity reorder is safe here: nothing downstream (no top-k).
    add_kernel<<<gAdd, blk, 0, stream>>>(A, B, n * 64);
    if (!fast)
        scale_full_kernel<<<gN, blk, 0, stream>>>(deg_out_i, deg_in_i, sarr, tarr, n);
    gemm_kernel<false><<<gemm_g128, blk, 0, stream>>>(A, W_dec1, nullptr, nullptr, sF, C, n, 256, 128);
    agg_bias_128_kernel<<<gAgg128, blk, 0, stream>>>(row_ptr, col, C, tF, b_dec1, out_f, n);

    (void)n_in; (void)out_size;
}

// Round 12
// 1312.686 us; speedup vs baseline: 1.2569x; 1.0925x over previous
//
#include <hip/hip_runtime.h>
#include <hip/hip_bf16.h>
#include <type_traits>

// ---------------- CSR build ----------------
__global__ void hist_kernel(const int* __restrict__ src, const int* __restrict__ dst,
                            int* __restrict__ deg_out, int* __restrict__ deg_in, int E) {
    int e = blockIdx.x * blockDim.x + threadIdx.x;
    if (e < E) {
        atomicAdd(&deg_out[src[e]], 1);
        atomicAdd(&deg_in[dst[e]], 1);
    }
}

__global__ void scan_kernel(const int* __restrict__ deg, int* __restrict__ row_ptr,
                            int* __restrict__ cursor, int n) {
    __shared__ int wsum[16];
    __shared__ int running;
    int tid = threadIdx.x, lane = tid & 63, wid = tid >> 6;
    if (tid == 0) running = 0;
    __syncthreads();
    for (int base = 0; base < n; base += 1024) {
        int i = base + tid;
        int v = (i < n) ? deg[i] : 0;
        int incl = v;
        #pragma unroll
        for (int off = 1; off < 64; off <<= 1) {
            int t = __shfl_up(incl, off);
            if (lane >= off) incl += t;
        }
        if (lane == 63) wsum[wid] = incl;
        __syncthreads();
        if (wid == 0 && lane < 16) {
            int s = wsum[lane], si = s;
            #pragma unroll
            for (int off = 1; off < 16; off <<= 1) {
                int t = __shfl_up(si, off);
                if (lane >= off) si += t;
            }
            wsum[lane] = si - s;  // exclusive
        }
        __syncthreads();
        int excl = running + wsum[wid] + (incl - v);
        if (i < n) { row_ptr[i] = excl; cursor[i] = excl; }
        __syncthreads();
        if (tid == 1023) running = excl + v;
        __syncthreads();
    }
    if (tid == 0) row_ptr[n] = running;
}

__global__ void fill_kernel(const int* __restrict__ src, const int* __restrict__ dst,
                            int* __restrict__ cursor, int* __restrict__ col, int E) {
    int e = blockIdx.x * blockDim.x + threadIdx.x;
    if (e < E) {
        int p = atomicAdd(&cursor[dst[e]], 1);
        col[p] = src[e];
    }
}

// deterministic neighbor order: insertion-sort each CSR row (avg deg 16)
__global__ void sort_rows_kernel(const int* __restrict__ row_ptr, int* __restrict__ col, int n) {
    int v = blockIdx.x * blockDim.x + threadIdx.x;
    if (v >= n) return;
    int e0 = row_ptr[v], e1 = row_ptr[v + 1];
    for (int i = e0 + 1; i < e1; ++i) {
        int key = col[i];
        int j = i - 1;
        while (j >= e0 && col[j] > key) { col[j + 1] = col[j]; --j; }
        col[j + 1] = key;
    }
}

// ---------------- masked degrees ----------------
__global__ void out_deg_mask_kernel(const int* __restrict__ src, const int* __restrict__ dst,
                                    const float* __restrict__ m, float* __restrict__ so, int E) {
    int e = blockIdx.x * blockDim.x + threadIdx.x;
    if (e < E) {
        float md = m[dst[e]];
        if (md != 0.f) atomicAdd(&so[src[e]], md);
    }
}

__global__ void in_deg_mask_kernel(const int* __restrict__ row_ptr, const int* __restrict__ col,
                                   const float* __restrict__ m, float* __restrict__ si, int n) {
    int v = blockIdx.x * blockDim.x + threadIdx.x;
    if (v < n) {
        float s = 0.f;
        int e1 = row_ptr[v + 1];
        for (int e = row_ptr[v]; e < e1; ++e) s += m[col[e]];
        si[v] = s;
    }
}

__global__ void scale_full_kernel(const int* __restrict__ dout, const int* __restrict__ din,
                                  float* __restrict__ s, float* __restrict__ t, int n) {
    int v = blockIdx.x * blockDim.x + threadIdx.x;
    if (v < n) {
        s[v] = 1.f / sqrtf((float)max(dout[v], 1));
        t[v] = 1.f / sqrtf((float)max(din[v], 1));
    }
}

__global__ void scale_mask_kernel(const float* __restrict__ gate, const float* __restrict__ mask,
                                  const float* __restrict__ so, const float* __restrict__ si,
                                  float* __restrict__ s, float* __restrict__ t, int n) {
    int v = blockIdx.x * blockDim.x + threadIdx.x;
    if (v < n) {
        s[v] = gate[v] * (1.f / sqrtf(fmaxf(so[v], 1.f)));
        t[v] = mask[v] * (1.f / sqrtf(fmaxf(si[v], 1.f)));
    }
}

// ---------------- aggregation from f32 FEATURES, F=128 (full graph) ----------------
__global__ void agg_feat_128_kernel(const int* __restrict__ row_ptr, const int* __restrict__ col,
                                    const float* __restrict__ X, const float* __restrict__ s,
                                    const float* __restrict__ t, float* __restrict__ out, int n) {
    int tid = threadIdx.x;
    int node = blockIdx.x * 8 + (tid >> 5);
    int f4 = tid & 31;
    if (node >= n) return;
    int e0 = row_ptr[node], e1 = row_ptr[node + 1];
    const float4* X4 = (const float4*)X;
    float ax = 0.f, ay = 0.f, az = 0.f, aw = 0.f;
    int e = e0;
    for (; e + 3 < e1; e += 4) {
        int u0 = col[e], u1 = col[e + 1], u2 = col[e + 2], u3 = col[e + 3];
        float s0 = s[u0], s1 = s[u1], s2 = s[u2], s3 = s[u3];
        float4 x0 = X4[(size_t)u0 * 32 + f4];
        float4 x1 = X4[(size_t)u1 * 32 + f4];
        float4 x2 = X4[(size_t)u2 * 32 + f4];
        float4 x3 = X4[(size_t)u3 * 32 + f4];
        ax += s0 * x0.x; ay += s0 * x0.y; az += s0 * x0.z; aw += s0 * x0.w;
        ax += s1 * x1.x; ay += s1 * x1.y; az += s1 * x1.z; aw += s1 * x1.w;
        ax += s2 * x2.x; ay += s2 * x2.y; az += s2 * x2.z; aw += s2 * x2.w;
        ax += s3 * x3.x; ay += s3 * x3.y; az += s3 * x3.z; aw += s3 * x3.w;
    }
    for (; e < e1; ++e) {
        int u = col[e];
        float sc = s[u];
        float4 q = X4[(size_t)u * 32 + f4];
        ax += sc * q.x; ay += sc * q.y; az += sc * q.z; aw += sc * q.w;
    }
    float tv = t[node];
    float4 r; r.x = ax * tv; r.y = ay * tv; r.z = az * tv; r.w = aw * tv;
    ((float4*)out)[(size_t)node * 32 + f4] = r;
}

// ---------------- aggregation over f32 workspace, F=256 ----------------
template <bool MASKED>
__global__ void agg_f32_256_kernel(const int* __restrict__ row_ptr, const int* __restrict__ col,
                                   const float* __restrict__ X, const float* __restrict__ s,
                                   const float* __restrict__ t, float* __restrict__ out, int n) {
    int tid = threadIdx.x;
    int node = blockIdx.x * 4 + (tid >> 6);
    int f4 = tid & 63;
    if (node >= n) return;
    float tv = t[node];
    if (MASKED && tv == 0.f) return;
    int e0 = row_ptr[node], e1 = row_ptr[node + 1];
    const float4* X4 = (const float4*)X;
    float ax = 0.f, ay = 0.f, az = 0.f, aw = 0.f;
    int e = e0;
    for (; e + 3 < e1; e += 4) {
        int u0 = col[e], u1 = col[e + 1], u2 = col[e + 2], u3 = col[e + 3];
        float s0 = s[u0], s1 = s[u1], s2 = s[u2], s3 = s[u3];
        if (!MASKED) {
            float4 x0 = X4[(size_t)u0 * 64 + f4];
            float4 x1 = X4[(size_t)u1 * 64 + f4];
            float4 x2 = X4[(size_t)u2 * 64 + f4];
            float4 x3 = X4[(size_t)u3 * 64 + f4];
            ax += s0 * x0.x; ay += s0 * x0.y; az += s0 * x0.z; aw += s0 * x0.w;
            ax += s1 * x1.x; ay += s1 * x1.y; az += s1 * x1.z; aw += s1 * x1.w;
            ax += s2 * x2.x; ay += s2 * x2.y; az += s2 * x2.z; aw += s2 * x2.w;
            ax += s3 * x3.x; ay += s3 * x3.y; az += s3 * x3.z; aw += s3 * x3.w;
        } else {
            if (s0 != 0.f) { float4 x = X4[(size_t)u0 * 64 + f4];
                ax += s0 * x.x; ay += s0 * x.y; az += s0 * x.z; aw += s0 * x.w; }
            if (s1 != 0.f) { float4 x = X4[(size_t)u1 * 64 + f4];
                ax += s1 * x.x; ay += s1 * x.y; az += s1 * x.z; aw += s1 * x.w; }
            if (s2 != 0.f) { float4 x = X4[(size_t)u2 * 64 + f4];
                ax += s2 * x.x; ay += s2 * x.y; az += s2 * x.z; aw += s2 * x.w; }
            if (s3 != 0.f) { float4 x = X4[(size_t)u3 * 64 + f4];
                ax += s3 * x.x; ay += s3 * x.y; az += s3 * x.z; aw += s3 * x.w; }
        }
    }
    for (; e < e1; ++e) {
        int u = col[e];
        float sc = s[u];
        if (!MASKED || sc != 0.f) {
            float4 xv = X4[(size_t)u * 64 + f4];
            ax += sc * xv.x; ay += sc * xv.y; az += sc * xv.z; aw += sc * xv.w;
        }
    }
    float4 r; r.x = ax * tv; r.y = ay * tv; r.z = az * tv; r.w = aw * tv;
    ((float4*)out)[(size_t)node * 64 + f4] = r;
}

// ---------------- post-GEMM 128-dim gather for dec1 (R11 reorder) ----------------
__global__ void agg_bias_128_kernel(const int* __restrict__ row_ptr, const int* __restrict__ col,
                                    const float* __restrict__ P, const float* __restrict__ t,
                                    const float* __restrict__ bias, float* __restrict__ out, int n) {
    int tid = threadIdx.x;
    int node = blockIdx.x * 8 + (tid >> 5);
    int f4 = tid & 31;
    if (node >= n) return;
    int e0 = row_ptr[node], e1 = row_ptr[node + 1];
    const float4* P4 = (const float4*)P;
    float ax = 0.f, ay = 0.f, az = 0.f, aw = 0.f;
    int e = e0;
    for (; e + 3 < e1; e += 4) {
        int u0 = col[e], u1 = col[e + 1], u2 = col[e + 2], u3 = col[e + 3];
        float4 x0 = P4[(size_t)u0 * 32 + f4];
        float4 x1 = P4[(size_t)u1 * 32 + f4];
        float4 x2 = P4[(size_t)u2 * 32 + f4];
        float4 x3 = P4[(size_t)u3 * 32 + f4];
        ax += x0.x; ay += x0.y; az += x0.z; aw += x0.w;
        ax += x1.x; ay += x1.y; az += x1.z; aw += x1.w;
        ax += x2.x; ay += x2.y; az += x2.z; aw += x2.w;
        ax += x3.x; ay += x3.y; az += x3.z; aw += x3.w;
    }
    for (; e < e1; ++e) {
        int u = col[e];
        float4 q = P4[(size_t)u * 32 + f4];
        ax += q.x; ay += q.y; az += q.z; aw += q.w;
    }
    float tv = t[node];
    float4 bv = ((const float4*)bias)[f4];
    float4 r;
    r.x = ax * tv + bv.x; r.y = ay * tv + bv.y;
    r.z = az * tv + bv.z; r.w = aw * tv + bv.w;
    ((float4*)out)[(size_t)node * 32 + f4] = r;
}

// ---------------- GEMM (full rows): out = act(A@W + b) * mask, opt rowscale ----------------
template <bool RELU>
__global__ __launch_bounds__(256) void gemm_kernel(const float* __restrict__ A,
                                                   const float* __restrict__ W,
                                                   const float* __restrict__ bias,
                                                   const float* __restrict__ mask,
                                                   const float* __restrict__ rowscale,
                                                   float* __restrict__ C, int M, int K, int Nn) {
    __shared__ float As[16][68];
    __shared__ float Bs[16][68];
    int tid = threadIdx.x;
    int bm = blockIdx.x * 64, bn = blockIdx.y * 64;
    int mA = tid >> 2, kqA = (tid & 3) * 4;
    int kB = tid >> 4, nqB = (tid & 15) * 4;
    int tn = (tid & 15) * 4, tm = (tid >> 4) * 4;
    float acc[4][4] = {};
    float rs = rowscale ? rowscale[bm + mA] : 1.f;
    for (int k0 = 0; k0 < K; k0 += 16) {
        float4 av = *(const float4*)(A + (size_t)(bm + mA) * K + k0 + kqA);
        As[kqA + 0][mA] = av.x * rs; As[kqA + 1][mA] = av.y * rs;
        As[kqA + 2][mA] = av.z * rs; As[kqA + 3][mA] = av.w * rs;
        float4 bv = *(const float4*)(W + (size_t)(k0 + kB) * Nn + bn + nqB);
        *(float4*)&Bs[kB][nqB] = bv;
        __syncthreads();
        #pragma unroll
        for (int kk = 0; kk < 16; ++kk) {
            float4 a = *(const float4*)&As[kk][tm];
            float4 b = *(const float4*)&Bs[kk][tn];
            float ar[4] = {a.x, a.y, a.z, a.w};
            float br[4] = {b.x, b.y, b.z, b.w};
            #pragma unroll
            for (int i2 = 0; i2 < 4; i2++)
                #pragma unroll
                for (int j = 0; j < 4; j++) acc[i2][j] += ar[i2] * br[j];
        }
        __syncthreads();
    }
    #pragma unroll
    for (int i2 = 0; i2 < 4; i2++) {
        int row = bm + tm + i2;
        if (row < M) {
            float mv = mask ? mask[row] : 1.f;
            #pragma unroll
            for (int j = 0; j < 4; j++) {
                float x = acc[i2][j] + (bias ? bias[bn + tn + j] : 0.f);
                if (RELU) x = fmaxf(x, 0.f);
                x *= mv;
                C[(size_t)row * Nn + bn + tn + j] = x;
            }
        }
    }
}

// ---------------- GEMM over compacted row list (R12) ----------------
// Computes rows idx[0..Mc): C[idx[i]] = relu(A[idx[i]]@W + b). Identical
// per-row arithmetic/order as gemm_kernel -> bit-identical stored values.
// Masked rows are left stale (handled by masked adds / s==0 guards downstream).
template <bool RELU>
__global__ __launch_bounds__(256) void gemm_rows_kernel(const float* __restrict__ A,
                                                        const float* __restrict__ W,
                                                        const float* __restrict__ bias,
                                                        const int* __restrict__ idx, int Mc,
                                                        float* __restrict__ C, int K, int Nn) {
    __shared__ float As[16][68];
    __shared__ float Bs[16][68];
    __shared__ int ridx[64];
    int tid = threadIdx.x;
    int bm = blockIdx.x * 64, bn = blockIdx.y * 64;
    if (tid < 64) {
        int r = bm + tid;
        ridx[tid] = (r < Mc) ? idx[r] : idx[0];
    }
    __syncthreads();
    int mA = tid >> 2, kqA = (tid & 3) * 4;
    int kB = tid >> 4, nqB = (tid & 15) * 4;
    int tn = (tid & 15) * 4, tm = (tid >> 4) * 4;
    int rA = ridx[mA];
    float acc[4][4] = {};
    for (int k0 = 0; k0 < K; k0 += 16) {
        float4 av = *(const float4*)(A + (size_t)rA * K + k0 + kqA);
        As[kqA + 0][mA] = av.x; As[kqA + 1][mA] = av.y;
        As[kqA + 2][mA] = av.z; As[kqA + 3][mA] = av.w;
        float4 bv = *(const float4*)(W + (size_t)(k0 + kB) * Nn + bn + nqB);
        *(float4*)&Bs[kB][nqB] = bv;
        __syncthreads();
        #pragma unroll
        for (int kk = 0; kk < 16; ++kk) {
            float4 a = *(const float4*)&As[kk][tm];
            float4 b = *(const float4*)&Bs[kk][tn];
            float ar[4] = {a.x, a.y, a.z, a.w};
            float br[4] = {b.x, b.y, b.z, b.w};
            #pragma unroll
            for (int i2 = 0; i2 < 4; i2++)
                #pragma unroll
                for (int j = 0; j < 4; j++) acc[i2][j] += ar[i2] * br[j];
        }
        __syncthreads();
    }
    #pragma unroll
    for (int i2 = 0; i2 < 4; i2++) {
        int r = bm + tm + i2;
        if (r < Mc) {
            int row = ridx[tm + i2];
            #pragma unroll
            for (int j = 0; j < 4; j++) {
                float x = acc[i2][j] + bias[bn + tn + j];
                if (RELU) x = fmaxf(x, 0.f);
                C[(size_t)row * Nn + bn + tn + j] = x;
            }
        }
    }
}

// ---------------- pooling score ----------------
__global__ void score_kernel(const float* __restrict__ H, const float* __restrict__ Wp,
                             const float* __restrict__ bp, const float* __restrict__ mask,
                             float* __restrict__ scores, float* __restrict__ keys, int n) {
    int lane = threadIdx.x & 63;
    int node = blockIdx.x * 4 + (threadIdx.x >> 6);
    if (node >= n) return;
    float4 hv = ((const float4*)(H + (size_t)node * 256))[lane];
    float4 wq = ((const float4*)Wp)[lane];
    float d = hv.x * wq.x + hv.y * wq.y + hv.z * wq.z + hv.w * wq.w;
    #pragma unroll
    for (int off = 32; off > 0; off >>= 1) d += __shfl_down(d, off);
    if (lane == 0) {
        float sc = 1.f / (1.f + expf(-(d + bp[0])));
        scores[node] = sc;
        keys[node] = (mask && mask[node] == 0.f) ? -1e9f : sc;
    }
}

// ---------------- top-K selection ----------------
__device__ __forceinline__ unsigned key_u(float f) {
    unsigned u = __float_as_uint(f);
    return (u & 0x80000000u) ? ~u : (u | 0x80000000u);
}

__device__ __forceinline__ void wave_hist_add(int* __restrict__ hist, unsigned bin, bool valid) {
    int lane = threadIdx.x & 63;
    while (true) {
        unsigned long long vmask = __ballot(valid);
        if (vmask == 0ull) break;
        int leader = __ffsll((long long)vmask) - 1;
        unsigned lbin = (unsigned)__shfl((int)bin, leader);
        bool match = valid && (bin == lbin);
        unsigned long long mmask = __ballot(match);
        if (lane == leader) atomicAdd(&hist[lbin], __popcll(mmask));
        if (match) valid = false;
    }
}

// -------- fallback: single block radix select --------
__global__ void topk_kernel(const float* __restrict__ keys, const float* __restrict__ scores,
                            float* __restrict__ nm, float* __restrict__ gate, int n, int K) {
    __shared__ int hist[256];
    __shared__ unsigned sh_prefix;
    __shared__ int sh_krem;
    __shared__ int sh_running;
    __shared__ int wsum[16];
    int tid = threadIdx.x, lane = tid & 63, wid = tid >> 6;
    if (tid == 0) { sh_prefix = 0u; sh_krem = K; sh_running = 0; }
    __syncthreads();
    for (int pass = 0; pass < 4; ++pass) {
        int shift = 24 - pass * 8;
        if (tid < 256) hist[tid] = 0;
        __syncthreads();
        unsigned pmask = (pass == 0) ? 0u : (0xFFFFFFFFu << (shift + 8));
        unsigned prefix = sh_prefix;
        for (int i = tid; i < n; i += 1024) {
            unsigned u = key_u(keys[i]);
            if ((u & pmask) == prefix) atomicAdd(&hist[(u >> shift) & 0xFF], 1);
        }
        __syncthreads();
        if (tid == 0) {
            int krem = sh_krem;
            int b;
            for (b = 255; b > 0; --b) {
                int c = hist[b];
                if (c >= krem) break;
                krem -= c;
            }
            sh_prefix = prefix | ((unsigned)b << shift);
            sh_krem = krem;
        }
        __syncthreads();
    }
    unsigned Tkey = sh_prefix;
    int need_eq = sh_krem;
    for (int base = 0; base < n; base += 1024) {
        int i = base + tid;
        unsigned u = 0; int flagv = 0;
        if (i < n) { u = key_u(keys[i]); flagv = (u == Tkey) ? 1 : 0; }
        unsigned long long bal = __ballot(flagv);
        int rank_w = __popcll(bal & ((1ull << lane) - 1ull));
        if (lane == 63) wsum[wid] = __popcll(bal);
        __syncthreads();
        int woff = 0;
        for (int w = 0; w < wid; ++w) woff += wsum[w];
        int grank = sh_running + woff + rank_w;
        if (i < n) {
            float v = (u > Tkey) ? 1.f : ((flagv && grank < need_eq) ? 1.f : 0.f);
            nm[i] = v;
            gate[i] = v * scores[i];
        }
        __syncthreads();
        if (tid == 0) {
            int tot = 0;
            for (int w = 0; w < 16; ++w) tot += wsum[w];
            sh_running += tot;
        }
        __syncthreads();
    }
}

// -------- fast path: grid-wide radix select, 2 passes of 16 bits --------
__global__ void topk_hist1(const float* __restrict__ keys, int n, int* __restrict__ hist) {
    int i = blockIdx.x * blockDim.x + threadIdx.x;
    unsigned bin = 0; bool valid = (i < n);
    if (valid) bin = key_u(keys[i]) >> 16;
    wave_hist_add(hist, bin, valid);
}

__global__ void topk_scan1(const int* __restrict__ hist, int K, int* __restrict__ sel) {
    __shared__ int arr[1024];
    int tid = threadIdx.x;
    int base = tid * 64;
    int local = 0;
    #pragma unroll 8
    for (int b = 0; b < 64; ++b) local += hist[base + b];
    arr[tid] = local;
    __syncthreads();
    for (int off = 1; off < 1024; off <<= 1) {
        int v = (tid + off < 1024) ? arr[tid + off] : 0;
        __syncthreads();
        arr[tid] += v;
        __syncthreads();
    }
    int above = arr[tid] - local;
    if (above < K && arr[tid] >= K) {
        int run = above;
        for (int b = base + 63; b >= base; --b) {
            int c = hist[b];
            if (run + c >= K) { sel[0] = b; sel[1] = K - run; break; }
            run += c;
        }
    }
}

__global__ void topk_hist2(const float* __restrict__ keys, int n, const int* __restrict__ sel,
                           int* __restrict__ hist) {
    int i = blockIdx.x * blockDim.x + threadIdx.x;
    unsigned bin = 0; bool valid = false;
    if (i < n) {
        unsigned u = key_u(keys[i]);
        if ((int)(u >> 16) == sel[0]) { bin = u & 0xFFFF; valid = true; }
    }
    wave_hist_add(hist, bin, valid);
}

__global__ void topk_scan2(const int* __restrict__ hist, int* __restrict__ sel,
                           int* __restrict__ tie_cnt) {
    __shared__ int arr[1024];
    int tid = threadIdx.x;
    if (tid == 0) *tie_cnt = 0;
    int K = sel[1];
    int base = tid * 64;
    int local = 0;
    #pragma unroll 8
    for (int b = 0; b < 64; ++b) local += hist[base + b];
    arr[tid] = local;
    __syncthreads();
    for (int off = 1; off < 1024; off <<= 1) {
        int v = (tid + off < 1024) ? arr[tid + off] : 0;
        __syncthreads();
        arr[tid] += v;
        __syncthreads();
    }
    int above = arr[tid] - local;
    if (above < K && arr[tid] >= K) {
        int run = above;
        for (int b = base + 63; b >= base; --b) {
            int c = hist[b];
            if (run + c >= K) {
                sel[2] = (int)((((unsigned)sel[0]) << 16) | (unsigned)b);
                sel[3] = K - run;
                break;
            }
            run += c;
        }
    }
}

__global__ void topk_mark(const float* __restrict__ keys, const float* __restrict__ scores,
                          const int* __restrict__ sel, float* __restrict__ nm,
                          float* __restrict__ gate, int* __restrict__ tie_list,
                          int* __restrict__ tie_cnt, int n) {
    int i = blockIdx.x * blockDim.x + threadIdx.x;
    if (i >= n) return;
    unsigned Tkey = (unsigned)sel[2];
    unsigned u = key_u(keys[i]);
    float v = 0.f;
    if (u > Tkey) v = 1.f;
    else if (u == Tkey) { int p = atomicAdd(tie_cnt, 1); tie_list[p] = i; }
    nm[i] = v;
    gate[i] = v * scores[i];
}

__global__ void topk_ties(const float* __restrict__ scores, const int* __restrict__ sel,
                          const int* __restrict__ tie_list, const int* __restrict__ tie_cnt,
                          float* __restrict__ nm, float* __restrict__ gate) {
    int cnt = *tie_cnt;
    int need = sel[3];
    for (int j = threadIdx.x; j < cnt; j += blockDim.x) {
        int idx = tie_list[j];
        int rank = 0;
        for (int k2 = 0; k2 < cnt; ++k2) rank += (tie_list[k2] < idx) ? 1 : 0;
        if (rank < need) { nm[idx] = 1.f; gate[idx] = scores[idx]; }
    }
}

// ---------------- selected-row compaction (order-independent) ----------------
__global__ void compact_kernel(const float* __restrict__ nm, int* __restrict__ idx,
                               int* __restrict__ cnt, int n) {
    int i = blockIdx.x * blockDim.x + threadIdx.x;
    if (i < n && nm[i] != 0.f) {
        int p = atomicAdd(cnt, 1);
        idx[p] = i;
    }
}

// ---------------- adds ----------------
// A = (mask ? A : 0) + B   (mask nullable -> plain A += B). Row = i>>6 (256 f / row).
__global__ void add_mask_kernel(float* __restrict__ A, const float* __restrict__ B,
                                const float* __restrict__ mask, int n4) {
    int i = blockIdx.x * blockDim.x + threadIdx.x;
    if (i < n4) {
        float4 a = ((float4*)A)[i];
        float4 b = ((const float4*)B)[i];
        if (mask && mask[i >> 6] == 0.f) { a.x = 0.f; a.y = 0.f; a.z = 0.f; a.w = 0.f; }
        a.x += b.x; a.y += b.y; a.z += b.z; a.w += b.w;
        ((float4*)A)[i] = a;
    }
}

extern "C" void kernel_launch(void* const* d_in, const int* in_sizes, int n_in,
                              void* d_out, int out_size, void* d_ws, size_t ws_size,
                              hipStream_t stream) {
    const int n = in_sizes[0] / 128;   // 50000
    const int E = in_sizes[1];         // 800000
    const int NPAD = ((n + 63) / 64) * 64;
    const int K1 = 25000, K2 = 12500;

    const float* features = (const float*)d_in[0];
    const int* src = (const int*)d_in[1];
    const int* dst = (const int*)d_in[2];
    const float* W_embed = (const float*)d_in[3];
    const float* b_embed = (const float*)d_in[4];
    const float* W_enc0  = (const float*)d_in[5];
    const float* b_enc0  = (const float*)d_in[6];
    const float* W_enc1  = (const float*)d_in[7];
    const float* b_enc1  = (const float*)d_in[8];
    const float* W_p0    = (const float*)d_in[9];
    const float* b_p0    = (const float*)d_in[10];
    const float* W_p1    = (const float*)d_in[11];
    const float* b_p1    = (const float*)d_in[12];
    const float* W_bot   = (const float*)d_in[13];
    const float* b_bot   = (const float*)d_in[14];
    const float* W_dec0  = (const float*)d_in[15];
    const float* b_dec0  = (const float*)d_in[16];
    const float* W_dec1  = (const float*)d_in[17];
    const float* b_dec1  = (const float*)d_in[18];
    float* out_f = (float*)d_out;

    char* ws = (char*)d_ws;
    size_t off = 0;
    auto alloc = [&](size_t bytes) -> void* {
        void* p = ws + off;
        off += (bytes + 255) & ~(size_t)255;
        return p;
    };
    (void)alloc(256);  // pad (R2 'flag' slot)
    int* row_ptr  = (int*)alloc((size_t)(n + 1) * 4);
    int* cursor   = (int*)alloc((size_t)n * 4);
    int* col      = (int*)alloc((size_t)E * 4);
    int* deg_out_i= (int*)alloc((size_t)n * 4);
    int* deg_in_i = (int*)alloc((size_t)n * 4);
    float* so_m1  = (float*)alloc((size_t)n * 4);
    float* si_m1  = (float*)alloc((size_t)n * 4);
    float* so_m2  = (float*)alloc((size_t)n * 4);
    float* si_m2  = (float*)alloc((size_t)n * 4);
    float* sarr   = (float*)alloc((size_t)n * 4);
    float* tarr   = (float*)alloc((size_t)n * 4);
    float* scores1= (float*)alloc((size_t)n * 4);
    float* keys1  = (float*)alloc((size_t)n * 4);
    float* scores2= (float*)alloc((size_t)n * 4);
    float* keys2  = (float*)alloc((size_t)n * 4);
    float* nm1    = (float*)alloc((size_t)n * 4);
    float* gate1  = (float*)alloc((size_t)n * 4);
    float* nm2    = (float*)alloc((size_t)n * 4);
    float* gate2  = (float*)alloc((size_t)n * 4);
    size_t big = (size_t)NPAD * 256 * 4;
    float* A = (float*)alloc(big);
    float* B = (float*)alloc(big);
    float* C = (float*)alloc(big);
    float* D = (float*)alloc(big);
    // ---- tail ----
    int* rhist    = (int*)alloc(65536 * 4);
    int* sel      = (int*)alloc(256);
    int* tie_cnt  = (int*)alloc(256);
    int* tie_list = (int*)alloc((size_t)n * 4);
    float* s0     = (float*)alloc((size_t)n * 4);
    float* t0     = (float*)alloc((size_t)n * 4);
    int* idx1     = (int*)alloc((size_t)n * 4);   // R12: m1 selected rows
    int* idx2     = (int*)alloc((size_t)n * 4);   // R12: m2 selected rows
    int* ccnt     = (int*)alloc(256);
    bool fast = (off <= ws_size);   // host-constant: same decision every call

    dim3 blk(256);
    int gE = (E + 255) / 256;
    int gN = (n + 255) / 256;
    int gAgg256 = (n + 3) / 4;
    int gAgg128 = (n + 7) / 8;
    int gScore = (n + 3) / 4;
    dim3 gemm_g(NPAD / 64, 4);
    dim3 gemm_g128(NPAD / 64, 2);
    dim3 gemm_gK1((K1 + 63) / 64, 4);   // compacted enc1 / dec0
    dim3 gemm_gK2((K2 + 63) / 64, 4);   // compacted bottleneck
    int gAdd = (n * 64 + 255) / 256;

    auto run_topk = [&](const float* keys, const float* scores, float* nm, float* gate, int K) {
        if (fast) {
            hipMemsetAsync(rhist, 0, 65536 * 4, stream);
            topk_hist1<<<gN, blk, 0, stream>>>(keys, n, rhist);
            topk_scan1<<<1, 1024, 0, stream>>>(rhist, K, sel);
            hipMemsetAsync(rhist, 0, 65536 * 4, stream);
            topk_hist2<<<gN, blk, 0, stream>>>(keys, n, sel, rhist);
            topk_scan2<<<1, 1024, 0, stream>>>(rhist, sel, tie_cnt);
            topk_mark<<<gN, blk, 0, stream>>>(keys, scores, sel, nm, gate, tie_list, tie_cnt, n);
            topk_ties<<<1, 256, 0, stream>>>(scores, sel, tie_list, tie_cnt, nm, gate);
        } else {
            topk_kernel<<<1, 1024, 0, stream>>>(keys, scores, nm, gate, n, K);
        }
    };
    float* sF = fast ? s0 : sarr;
    float* tF = fast ? t0 : tarr;

    // ---- CSR build ----
    hipMemsetAsync(deg_out_i, 0, (size_t)n * 4, stream);
    hipMemsetAsync(deg_in_i, 0, (size_t)n * 4, stream);
    hist_kernel<<<gE, blk, 0, stream>>>(src, dst, deg_out_i, deg_in_i, E);
    scan_kernel<<<1, 1024, 0, stream>>>(deg_in_i, row_ptr, cursor, n);
    fill_kernel<<<gE, blk, 0, stream>>>(src, dst, cursor, col, E);
    sort_rows_kernel<<<gN, blk, 0, stream>>>(row_ptr, col, n);

    // ---- full-graph degree scales (once) ----
    scale_full_kernel<<<gN, blk, 0, stream>>>(deg_out_i, deg_in_i, sF, tF, n);

    // ---- embed GCN (full graph) -> A ----
    agg_feat_128_kernel<<<gAgg128, blk, 0, stream>>>(row_ptr, col, features, sF, tF, D, n);
    gemm_kernel<true><<<gemm_g, blk, 0, stream>>>(D, W_embed, b_embed, nullptr, nullptr, A, n, 128, 256);

    // ---- enc0 (full graph); hidden0 = B ----
    agg_f32_256_kernel<false><<<gAgg256, blk, 0, stream>>>(row_ptr, col, A, sF, tF, D, n);
    gemm_kernel<true><<<gemm_g, blk, 0, stream>>>(D, W_enc0, b_enc0, nullptr, nullptr, B, n, 256, 256);

    // ---- pool0 ----
    score_kernel<<<gScore, blk, 0, stream>>>(B, W_p0, b_p0, nullptr, scores1, keys1, n);
    run_topk(keys1, scores1, nm1, gate1, K1);
    if (fast) {
        hipMemsetAsync(ccnt, 0, 4, stream);
        compact_kernel<<<gN, blk, 0, stream>>>(nm1, idx1, ccnt, n);
    }

    // ---- enc1 (mask m1, gated input); hidden1 = C ----
    hipMemsetAsync(so_m1, 0, (size_t)n * 4, stream);
    out_deg_mask_kernel<<<gE, blk, 0, stream>>>(src, dst, nm1, so_m1, E);
    in_deg_mask_kernel<<<gN, blk, 0, stream>>>(row_ptr, col, nm1, si_m1, n);
    scale_mask_kernel<<<gN, blk, 0, stream>>>(gate1, nm1, so_m1, si_m1, sarr, tarr, n);
    agg_f32_256_kernel<true><<<gAgg256, blk, 0, stream>>>(row_ptr, col, B, sarr, tarr, D, n);
    if (fast)
        gemm_rows_kernel<true><<<gemm_gK1, blk, 0, stream>>>(D, W_enc1, b_enc1, idx1, K1, C, 256, 256);
    else
        gemm_kernel<true><<<gemm_g, blk, 0, stream>>>(D, W_enc1, b_enc1, nm1, nullptr, C, n, 256, 256);

    // ---- pool1 ----
    score_kernel<<<gScore, blk, 0, stream>>>(C, W_p1, b_p1, nm1, scores2, keys2, n);
    run_topk(keys2, scores2, nm2, gate2, K2);
    if (fast) {
        hipMemsetAsync(ccnt + 1, 0, 4, stream);
        compact_kernel<<<gN, blk, 0, stream>>>(nm2, idx2, ccnt + 1, n);
    }

    // ---- bottleneck (mask m2, gated input) -> A ----
    hipMemsetAsync(so_m2, 0, (size_t)n * 4, stream);
    out_deg_mask_kernel<<<gE, blk, 0, stream>>>(src, dst, nm2, so_m2, E);
    in_deg_mask_kernel<<<gN, blk, 0, stream>>>(row_ptr, col, nm2, si_m2, n);
    scale_mask_kernel<<<gN, blk, 0, stream>>>(gate2, nm2, so_m2, si_m2, sarr, tarr, n);
    agg_f32_256_kernel<true><<<gAgg256, blk, 0, stream>>>(row_ptr, col, C, sarr, tarr, D, n);
    if (fast)
        gemm_rows_kernel<true><<<gemm_gK2, blk, 0, stream>>>(D, W_bot, b_bot, idx2, K2, A, 256, 256);
    else
        gemm_kernel<true><<<gemm_g, blk, 0, stream>>>(D, W_bot, b_bot, nm2, nullptr, A, n, 256, 256);

    // ---- dec0: h = (m2? bot : 0) + hidden1, GCN mask m1 -> A ----
    add_mask_kernel<<<gAdd, blk, 0, stream>>>(A, C, fast ? nm2 : nullptr, n * 64);
    scale_mask_kernel<<<gN, blk, 0, stream>>>(nm1, nm1, so_m1, si_m1, sarr, tarr, n);
    agg_f32_256_kernel<true><<<gAgg256, blk, 0, stream>>>(row_ptr, col, A, sarr, tarr, D, n);
    if (fast)
        gemm_rows_kernel<true><<<gemm_gK1, blk, 0, stream>>>(D, W_dec0, b_dec0, idx1, K1, A, 256, 256);
    else
        gemm_kernel<true><<<gemm_g, blk, 0, stream>>>(D, W_dec0, b_dec0, nm1, nullptr, A, n, 256, 256);

    // ---- dec1 (reordered, final layer): h = (m1? dec0 : 0) + hidden0;
    //      P = (s0 .* h) @ W_dec1 -> C;  out_v = t0[v]*sum_N(v) P + b_dec1
    add_mask_kernel<<<gAdd, blk, 0, stream>>>(A, B, fast ? nm1 : nullptr, n * 64);
    if (!fast)
        scale_full_kernel<<<gN, blk, 0, stream>>>(deg_out_i, deg_in_i, sarr, tarr, n);
    gemm_kernel<false><<<gemm_g128, blk, 0, stream>>>(A, W_dec1, nullptr, nullptr, sF, C, n, 256, 128);
    agg_bias_128_kernel<<<gAgg128, blk, 0, stream>>>(row_ptr, col, C, tF, b_dec1, out_f, n);

    (void)n_in; (void)out_size;
}

// Round 13
// 1311.928 us; speedup vs baseline: 1.2576x; 1.0006x over previous
//
#include <hip/hip_runtime.h>
#include <hip/hip_bf16.h>
#include <type_traits>

// ---------------- CSR build ----------------
__global__ void hist_kernel(const int* __restrict__ src, const int* __restrict__ dst,
                            int* __restrict__ deg_out, int* __restrict__ deg_in, int E) {
    int e = blockIdx.x * blockDim.x + threadIdx.x;
    if (e < E) {
        atomicAdd(&deg_out[src[e]], 1);
        atomicAdd(&deg_in[dst[e]], 1);
    }
}

__global__ void scan_kernel(const int* __restrict__ deg, int* __restrict__ row_ptr,
                            int* __restrict__ cursor, int n) {
    __shared__ int wsum[16];
    __shared__ int running;
    int tid = threadIdx.x, lane = tid & 63, wid = tid >> 6;
    if (tid == 0) running = 0;
    __syncthreads();
    for (int base = 0; base < n; base += 1024) {
        int i = base + tid;
        int v = (i < n) ? deg[i] : 0;
        int incl = v;
        #pragma unroll
        for (int off = 1; off < 64; off <<= 1) {
            int t = __shfl_up(incl, off);
            if (lane >= off) incl += t;
        }
        if (lane == 63) wsum[wid] = incl;
        __syncthreads();
        if (wid == 0 && lane < 16) {
            int s = wsum[lane], si = s;
            #pragma unroll
            for (int off = 1; off < 16; off <<= 1) {
                int t = __shfl_up(si, off);
                if (lane >= off) si += t;
            }
            wsum[lane] = si - s;  // exclusive
        }
        __syncthreads();
        int excl = running + wsum[wid] + (incl - v);
        if (i < n) { row_ptr[i] = excl; cursor[i] = excl; }
        __syncthreads();
        if (tid == 1023) running = excl + v;
        __syncthreads();
    }
    if (tid == 0) row_ptr[n] = running;
}

__global__ void fill_kernel(const int* __restrict__ src, const int* __restrict__ dst,
                            int* __restrict__ cursor, int* __restrict__ col, int E) {
    int e = blockIdx.x * blockDim.x + threadIdx.x;
    if (e < E) {
        int p = atomicAdd(&cursor[dst[e]], 1);
        col[p] = src[e];
    }
}

// deterministic neighbor order: insertion-sort each CSR row (avg deg 16)
__global__ void sort_rows_kernel(const int* __restrict__ row_ptr, int* __restrict__ col, int n) {
    int v = blockIdx.x * blockDim.x + threadIdx.x;
    if (v >= n) return;
    int e0 = row_ptr[v], e1 = row_ptr[v + 1];
    for (int i = e0 + 1; i < e1; ++i) {
        int key = col[i];
        int j = i - 1;
        while (j >= e0 && col[j] > key) { col[j + 1] = col[j]; --j; }
        col[j + 1] = key;
    }
}

// ---------------- masked degrees ----------------
__global__ void out_deg_mask_kernel(const int* __restrict__ src, const int* __restrict__ dst,
                                    const float* __restrict__ m, float* __restrict__ so, int E) {
    int e = blockIdx.x * blockDim.x + threadIdx.x;
    if (e < E) {
        float md = m[dst[e]];
        if (md != 0.f) atomicAdd(&so[src[e]], md);
    }
}

__global__ void in_deg_mask_kernel(const int* __restrict__ row_ptr, const int* __restrict__ col,
                                   const float* __restrict__ m, float* __restrict__ si, int n) {
    int v = blockIdx.x * blockDim.x + threadIdx.x;
    if (v < n) {
        float s = 0.f;
        int e1 = row_ptr[v + 1];
        for (int e = row_ptr[v]; e < e1; ++e) s += m[col[e]];
        si[v] = s;
    }
}

__global__ void scale_full_kernel(const int* __restrict__ dout, const int* __restrict__ din,
                                  float* __restrict__ s, float* __restrict__ t, int n) {
    int v = blockIdx.x * blockDim.x + threadIdx.x;
    if (v < n) {
        s[v] = 1.f / sqrtf((float)max(dout[v], 1));
        t[v] = 1.f / sqrtf((float)max(din[v], 1));
    }
}

__global__ void scale_mask_kernel(const float* __restrict__ gate, const float* __restrict__ mask,
                                  const float* __restrict__ so, const float* __restrict__ si,
                                  float* __restrict__ s, float* __restrict__ t, int n) {
    int v = blockIdx.x * blockDim.x + threadIdx.x;
    if (v < n) {
        s[v] = gate[v] * (1.f / sqrtf(fmaxf(so[v], 1.f)));
        t[v] = mask[v] * (1.f / sqrtf(fmaxf(si[v], 1.f)));
    }
}

// ---------------- aggregation from f32 FEATURES, F=128 (full graph) ----------------
__global__ void agg_feat_128_kernel(const int* __restrict__ row_ptr, const int* __restrict__ col,
                                    const float* __restrict__ X, const float* __restrict__ s,
                                    const float* __restrict__ t, float* __restrict__ out, int n) {
    int tid = threadIdx.x;
    int node = blockIdx.x * 8 + (tid >> 5);
    int f4 = tid & 31;
    if (node >= n) return;
    int e0 = row_ptr[node], e1 = row_ptr[node + 1];
    const float4* X4 = (const float4*)X;
    float ax = 0.f, ay = 0.f, az = 0.f, aw = 0.f;
    int e = e0;
    for (; e + 3 < e1; e += 4) {
        int u0 = col[e], u1 = col[e + 1], u2 = col[e + 2], u3 = col[e + 3];
        float s0 = s[u0], s1 = s[u1], s2 = s[u2], s3 = s[u3];
        float4 x0 = X4[(size_t)u0 * 32 + f4];
        float4 x1 = X4[(size_t)u1 * 32 + f4];
        float4 x2 = X4[(size_t)u2 * 32 + f4];
        float4 x3 = X4[(size_t)u3 * 32 + f4];
        ax += s0 * x0.x; ay += s0 * x0.y; az += s0 * x0.z; aw += s0 * x0.w;
        ax += s1 * x1.x; ay += s1 * x1.y; az += s1 * x1.z; aw += s1 * x1.w;
        ax += s2 * x2.x; ay += s2 * x2.y; az += s2 * x2.z; aw += s2 * x2.w;
        ax += s3 * x3.x; ay += s3 * x3.y; az += s3 * x3.z; aw += s3 * x3.w;
    }
    for (; e < e1; ++e) {
        int u = col[e];
        float sc = s[u];
        float4 q = X4[(size_t)u * 32 + f4];
        ax += sc * q.x; ay += sc * q.y; az += sc * q.z; aw += sc * q.w;
    }
    float tv = t[node];
    float4 r; r.x = ax * tv; r.y = ay * tv; r.z = az * tv; r.w = aw * tv;
    ((float4*)out)[(size_t)node * 32 + f4] = r;
}

// ---------------- aggregation over f32 workspace, F=256 ----------------
template <bool MASKED>
__global__ void agg_f32_256_kernel(const int* __restrict__ row_ptr, const int* __restrict__ col,
                                   const float* __restrict__ X, const float* __restrict__ s,
                                   const float* __restrict__ t, float* __restrict__ out, int n) {
    int tid = threadIdx.x;
    int node = blockIdx.x * 4 + (tid >> 6);
    int f4 = tid & 63;
    if (node >= n) return;
    float tv = t[node];
    if (MASKED && tv == 0.f) return;
    int e0 = row_ptr[node], e1 = row_ptr[node + 1];
    const float4* X4 = (const float4*)X;
    float ax = 0.f, ay = 0.f, az = 0.f, aw = 0.f;
    int e = e0;
    for (; e + 3 < e1; e += 4) {
        int u0 = col[e], u1 = col[e + 1], u2 = col[e + 2], u3 = col[e + 3];
        float s0 = s[u0], s1 = s[u1], s2 = s[u2], s3 = s[u3];
        if (!MASKED) {
            float4 x0 = X4[(size_t)u0 * 64 + f4];
            float4 x1 = X4[(size_t)u1 * 64 + f4];
            float4 x2 = X4[(size_t)u2 * 64 + f4];
            float4 x3 = X4[(size_t)u3 * 64 + f4];
            ax += s0 * x0.x; ay += s0 * x0.y; az += s0 * x0.z; aw += s0 * x0.w;
            ax += s1 * x1.x; ay += s1 * x1.y; az += s1 * x1.z; aw += s1 * x1.w;
            ax += s2 * x2.x; ay += s2 * x2.y; az += s2 * x2.z; aw += s2 * x2.w;
            ax += s3 * x3.x; ay += s3 * x3.y; az += s3 * x3.z; aw += s3 * x3.w;
        } else {
            if (s0 != 0.f) { float4 x = X4[(size_t)u0 * 64 + f4];
                ax += s0 * x.x; ay += s0 * x.y; az += s0 * x.z; aw += s0 * x.w; }
            if (s1 != 0.f) { float4 x = X4[(size_t)u1 * 64 + f4];
                ax += s1 * x.x; ay += s1 * x.y; az += s1 * x.z; aw += s1 * x.w; }
            if (s2 != 0.f) { float4 x = X4[(size_t)u2 * 64 + f4];
                ax += s2 * x.x; ay += s2 * x.y; az += s2 * x.z; aw += s2 * x.w; }
            if (s3 != 0.f) { float4 x = X4[(size_t)u3 * 64 + f4];
                ax += s3 * x.x; ay += s3 * x.y; az += s3 * x.z; aw += s3 * x.w; }
        }
    }
    for (; e < e1; ++e) {
        int u = col[e];
        float sc = s[u];
        if (!MASKED || sc != 0.f) {
            float4 xv = X4[(size_t)u * 64 + f4];
            ax += sc * xv.x; ay += sc * xv.y; az += sc * xv.z; aw += sc * xv.w;
        }
    }
    float4 r; r.x = ax * tv; r.y = ay * tv; r.z = az * tv; r.w = aw * tv;
    ((float4*)out)[(size_t)node * 64 + f4] = r;
}

// ---------------- post-GEMM 128-dim gather for dec1 (R11 reorder) ----------------
__global__ void agg_bias_128_kernel(const int* __restrict__ row_ptr, const int* __restrict__ col,
                                    const float* __restrict__ P, const float* __restrict__ t,
                                    const float* __restrict__ bias, float* __restrict__ out, int n) {
    int tid = threadIdx.x;
    int node = blockIdx.x * 8 + (tid >> 5);
    int f4 = tid & 31;
    if (node >= n) return;
    int e0 = row_ptr[node], e1 = row_ptr[node + 1];
    const float4* P4 = (const float4*)P;
    float ax = 0.f, ay = 0.f, az = 0.f, aw = 0.f;
    int e = e0;
    for (; e + 3 < e1; e += 4) {
        int u0 = col[e], u1 = col[e + 1], u2 = col[e + 2], u3 = col[e + 3];
        float4 x0 = P4[(size_t)u0 * 32 + f4];
        float4 x1 = P4[(size_t)u1 * 32 + f4];
        float4 x2 = P4[(size_t)u2 * 32 + f4];
        float4 x3 = P4[(size_t)u3 * 32 + f4];
        ax += x0.x; ay += x0.y; az += x0.z; aw += x0.w;
        ax += x1.x; ay += x1.y; az += x1.z; aw += x1.w;
        ax += x2.x; ay += x2.y; az += x2.z; aw += x2.w;
        ax += x3.x; ay += x3.y; az += x3.z; aw += x3.w;
    }
    for (; e < e1; ++e) {
        int u = col[e];
        float4 q = P4[(size_t)u * 32 + f4];
        ax += q.x; ay += q.y; az += q.z; aw += q.w;
    }
    float tv = t[node];
    float4 bv = ((const float4*)bias)[f4];
    float4 r;
    r.x = ax * tv + bv.x; r.y = ay * tv + bv.y;
    r.z = az * tv + bv.z; r.w = aw * tv + bv.w;
    ((float4*)out)[(size_t)node * 32 + f4] = r;
}

// ---------------- GEMM (full rows): 64x128 tile, 4x(4+4) micro-tile ----------------
// R13: thread owns cols {tn..tn+3} U {tn+64..tn+67}, tn=(tid&15)*4 -> B-read
// starting banks {0,4,...,28}x2 = 2-way (free), vs R9's 4-way. 0.75 B/FLOP.
// K accumulation order (k0 outer, kk ascending) identical -> bit-identical.
template <bool RELU>
__global__ __launch_bounds__(256) void gemm_kernel(const float* __restrict__ A,
                                                   const float* __restrict__ W,
                                                   const float* __restrict__ bias,
                                                   const float* __restrict__ mask,
                                                   const float* __restrict__ rowscale,
                                                   float* __restrict__ C, int M, int K, int Nn) {
    __shared__ float As[16][68];
    __shared__ float Bs[16][132];
    int tid = threadIdx.x;
    int bm = blockIdx.x * 64, bn = blockIdx.y * 128;
    int mA = tid >> 2, kqA = (tid & 3) * 4;
    int kB = tid >> 4, nqB = (tid & 15) * 8;
    int tm = (tid >> 4) * 4, tn = (tid & 15) * 4;
    float acc[4][8] = {};
    float rs = rowscale ? rowscale[bm + mA] : 1.f;
    for (int k0 = 0; k0 < K; k0 += 16) {
        float4 av = *(const float4*)(A + (size_t)(bm + mA) * K + k0 + kqA);
        As[kqA + 0][mA] = av.x * rs; As[kqA + 1][mA] = av.y * rs;
        As[kqA + 2][mA] = av.z * rs; As[kqA + 3][mA] = av.w * rs;
        const float* wp = W + (size_t)(k0 + kB) * Nn + bn + nqB;
        *(float4*)&Bs[kB][nqB]     = *(const float4*)wp;
        *(float4*)&Bs[kB][nqB + 4] = *(const float4*)(wp + 4);
        __syncthreads();
        #pragma unroll
        for (int kk = 0; kk < 16; ++kk) {
            float4 a  = *(const float4*)&As[kk][tm];
            float4 b0 = *(const float4*)&Bs[kk][tn];
            float4 b1 = *(const float4*)&Bs[kk][tn + 64];
            float ar[4] = {a.x, a.y, a.z, a.w};
            float br[8] = {b0.x, b0.y, b0.z, b0.w, b1.x, b1.y, b1.z, b1.w};
            #pragma unroll
            for (int i2 = 0; i2 < 4; i2++)
                #pragma unroll
                for (int j = 0; j < 8; j++) acc[i2][j] += ar[i2] * br[j];
        }
        __syncthreads();
    }
    #pragma unroll
    for (int i2 = 0; i2 < 4; i2++) {
        int row = bm + tm + i2;
        if (row < M) {
            float mv = mask ? mask[row] : 1.f;
            float o[8];
            #pragma unroll
            for (int j = 0; j < 8; j++) {
                int cj = (j < 4) ? (tn + j) : (64 + tn + j - 4);
                float x = acc[i2][j] + (bias ? bias[bn + cj] : 0.f);
                if (RELU) x = fmaxf(x, 0.f);
                o[j] = x * mv;
            }
            float* cp = C + (size_t)row * Nn + bn;
            *(float4*)(cp + tn)      = make_float4(o[0], o[1], o[2], o[3]);
            *(float4*)(cp + 64 + tn) = make_float4(o[4], o[5], o[6], o[7]);
        }
    }
}

// ---------------- GEMM over compacted row list (R12 + R13 tiling) ----------------
template <bool RELU>
__global__ __launch_bounds__(256) void gemm_rows_kernel(const float* __restrict__ A,
                                                        const float* __restrict__ W,
                                                        const float* __restrict__ bias,
                                                        const int* __restrict__ idx, int Mc,
                                                        float* __restrict__ C, int K, int Nn) {
    __shared__ float As[16][68];
    __shared__ float Bs[16][132];
    __shared__ int ridx[64];
    int tid = threadIdx.x;
    int bm = blockIdx.x * 64, bn = blockIdx.y * 128;
    if (tid < 64) {
        int r = bm + tid;
        ridx[tid] = (r < Mc) ? idx[r] : idx[0];
    }
    __syncthreads();
    int mA = tid >> 2, kqA = (tid & 3) * 4;
    int kB = tid >> 4, nqB = (tid & 15) * 8;
    int tm = (tid >> 4) * 4, tn = (tid & 15) * 4;
    int rA = ridx[mA];
    float acc[4][8] = {};
    for (int k0 = 0; k0 < K; k0 += 16) {
        float4 av = *(const float4*)(A + (size_t)rA * K + k0 + kqA);
        As[kqA + 0][mA] = av.x; As[kqA + 1][mA] = av.y;
        As[kqA + 2][mA] = av.z; As[kqA + 3][mA] = av.w;
        const float* wp = W + (size_t)(k0 + kB) * Nn + bn + nqB;
        *(float4*)&Bs[kB][nqB]     = *(const float4*)wp;
        *(float4*)&Bs[kB][nqB + 4] = *(const float4*)(wp + 4);
        __syncthreads();
        #pragma unroll
        for (int kk = 0; kk < 16; ++kk) {
            float4 a  = *(const float4*)&As[kk][tm];
            float4 b0 = *(const float4*)&Bs[kk][tn];
            float4 b1 = *(const float4*)&Bs[kk][tn + 64];
            float ar[4] = {a.x, a.y, a.z, a.w};
            float br[8] = {b0.x, b0.y, b0.z, b0.w, b1.x, b1.y, b1.z, b1.w};
            #pragma unroll
            for (int i2 = 0; i2 < 4; i2++)
                #pragma unroll
                for (int j = 0; j < 8; j++) acc[i2][j] += ar[i2] * br[j];
        }
        __syncthreads();
    }
    #pragma unroll
    for (int i2 = 0; i2 < 4; i2++) {
        int r = bm + tm + i2;
        if (r < Mc) {
            int row = ridx[tm + i2];
            float o[8];
            #pragma unroll
            for (int j = 0; j < 8; j++) {
                int cj = (j < 4) ? (tn + j) : (64 + tn + j - 4);
                float x = acc[i2][j] + bias[bn + cj];
                if (RELU) x = fmaxf(x, 0.f);
                o[j] = x;
            }
            float* cp = C + (size_t)row * Nn + bn;
            *(float4*)(cp + tn)      = make_float4(o[0], o[1], o[2], o[3]);
            *(float4*)(cp + 64 + tn) = make_float4(o[4], o[5], o[6], o[7]);
        }
    }
}

// ---------------- pooling score ----------------
__global__ void score_kernel(const float* __restrict__ H, const float* __restrict__ Wp,
                             const float* __restrict__ bp, const float* __restrict__ mask,
                             float* __restrict__ scores, float* __restrict__ keys, int n) {
    int lane = threadIdx.x & 63;
    int node = blockIdx.x * 4 + (threadIdx.x >> 6);
    if (node >= n) return;
    float4 hv = ((const float4*)(H + (size_t)node * 256))[lane];
    float4 wq = ((const float4*)Wp)[lane];
    float d = hv.x * wq.x + hv.y * wq.y + hv.z * wq.z + hv.w * wq.w;
    #pragma unroll
    for (int off = 32; off > 0; off >>= 1) d += __shfl_down(d, off);
    if (lane == 0) {
        float sc = 1.f / (1.f + expf(-(d + bp[0])));
        scores[node] = sc;
        keys[node] = (mask && mask[node] == 0.f) ? -1e9f : sc;
    }
}

// ---------------- top-K selection ----------------
__device__ __forceinline__ unsigned key_u(float f) {
    unsigned u = __float_as_uint(f);
    return (u & 0x80000000u) ? ~u : (u | 0x80000000u);
}

__device__ __forceinline__ void wave_hist_add(int* __restrict__ hist, unsigned bin, bool valid) {
    int lane = threadIdx.x & 63;
    while (true) {
        unsigned long long vmask = __ballot(valid);
        if (vmask == 0ull) break;
        int leader = __ffsll((long long)vmask) - 1;
        unsigned lbin = (unsigned)__shfl((int)bin, leader);
        bool match = valid && (bin == lbin);
        unsigned long long mmask = __ballot(match);
        if (lane == leader) atomicAdd(&hist[lbin], __popcll(mmask));
        if (match) valid = false;
    }
}

// -------- fallback: single block radix select --------
__global__ void topk_kernel(const float* __restrict__ keys, const float* __restrict__ scores,
                            float* __restrict__ nm, float* __restrict__ gate, int n, int K) {
    __shared__ int hist[256];
    __shared__ unsigned sh_prefix;
    __shared__ int sh_krem;
    __shared__ int sh_running;
    __shared__ int wsum[16];
    int tid = threadIdx.x, lane = tid & 63, wid = tid >> 6;
    if (tid == 0) { sh_prefix = 0u; sh_krem = K; sh_running = 0; }
    __syncthreads();
    for (int pass = 0; pass < 4; ++pass) {
        int shift = 24 - pass * 8;
        if (tid < 256) hist[tid] = 0;
        __syncthreads();
        unsigned pmask = (pass == 0) ? 0u : (0xFFFFFFFFu << (shift + 8));
        unsigned prefix = sh_prefix;
        for (int i = tid; i < n; i += 1024) {
            unsigned u = key_u(keys[i]);
            if ((u & pmask) == prefix) atomicAdd(&hist[(u >> shift) & 0xFF], 1);
        }
        __syncthreads();
        if (tid == 0) {
            int krem = sh_krem;
            int b;
            for (b = 255; b > 0; --b) {
                int c = hist[b];
                if (c >= krem) break;
                krem -= c;
            }
            sh_prefix = prefix | ((unsigned)b << shift);
            sh_krem = krem;
        }
        __syncthreads();
    }
    unsigned Tkey = sh_prefix;
    int need_eq = sh_krem;
    for (int base = 0; base < n; base += 1024) {
        int i = base + tid;
        unsigned u = 0; int flagv = 0;
        if (i < n) { u = key_u(keys[i]); flagv = (u == Tkey) ? 1 : 0; }
        unsigned long long bal = __ballot(flagv);
        int rank_w = __popcll(bal & ((1ull << lane) - 1ull));
        if (lane == 63) wsum[wid] = __popcll(bal);
        __syncthreads();
        int woff = 0;
        for (int w = 0; w < wid; ++w) woff += wsum[w];
        int grank = sh_running + woff + rank_w;
        if (i < n) {
            float v = (u > Tkey) ? 1.f : ((flagv && grank < need_eq) ? 1.f : 0.f);
            nm[i] = v;
            gate[i] = v * scores[i];
        }
        __syncthreads();
        if (tid == 0) {
            int tot = 0;
            for (int w = 0; w < 16; ++w) tot += wsum[w];
            sh_running += tot;
        }
        __syncthreads();
    }
}

// -------- fast path: grid-wide radix select, 2 passes of 16 bits --------
__global__ void topk_hist1(const float* __restrict__ keys, int n, int* __restrict__ hist) {
    int i = blockIdx.x * blockDim.x + threadIdx.x;
    unsigned bin = 0; bool valid = (i < n);
    if (valid) bin = key_u(keys[i]) >> 16;
    wave_hist_add(hist, bin, valid);
}

__global__ void topk_scan1(const int* __restrict__ hist, int K, int* __restrict__ sel) {
    __shared__ int arr[1024];
    int tid = threadIdx.x;
    int base = tid * 64;
    int local = 0;
    #pragma unroll 8
    for (int b = 0; b < 64; ++b) local += hist[base + b];
    arr[tid] = local;
    __syncthreads();
    for (int off = 1; off < 1024; off <<= 1) {
        int v = (tid + off < 1024) ? arr[tid + off] : 0;
        __syncthreads();
        arr[tid] += v;
        __syncthreads();
    }
    int above = arr[tid] - local;
    if (above < K && arr[tid] >= K) {
        int run = above;
        for (int b = base + 63; b >= base; --b) {
            int c = hist[b];
            if (run + c >= K) { sel[0] = b; sel[1] = K - run; break; }
            run += c;
        }
    }
}

__global__ void topk_hist2(const float* __restrict__ keys, int n, const int* __restrict__ sel,
                           int* __restrict__ hist) {
    int i = blockIdx.x * blockDim.x + threadIdx.x;
    unsigned bin = 0; bool valid = false;
    if (i < n) {
        unsigned u = key_u(keys[i]);
        if ((int)(u >> 16) == sel[0]) { bin = u & 0xFFFF; valid = true; }
    }
    wave_hist_add(hist, bin, valid);
}

__global__ void topk_scan2(const int* __restrict__ hist, int* __restrict__ sel,
                           int* __restrict__ tie_cnt) {
    __shared__ int arr[1024];
    int tid = threadIdx.x;
    if (tid == 0) *tie_cnt = 0;
    int K = sel[1];
    int base = tid * 64;
    int local = 0;
    #pragma unroll 8
    for (int b = 0; b < 64; ++b) local += hist[base + b];
    arr[tid] = local;
    __syncthreads();
    for (int off = 1; off < 1024; off <<= 1) {
        int v = (tid + off < 1024) ? arr[tid + off] : 0;
        __syncthreads();
        arr[tid] += v;
        __syncthreads();
    }
    int above = arr[tid] - local;
    if (above < K && arr[tid] >= K) {
        int run = above;
        for (int b = base + 63; b >= base; --b) {
            int c = hist[b];
            if (run + c >= K) {
                sel[2] = (int)((((unsigned)sel[0]) << 16) | (unsigned)b);
                sel[3] = K - run;
                break;
            }
            run += c;
        }
    }
}

__global__ void topk_mark(const float* __restrict__ keys, const float* __restrict__ scores,
                          const int* __restrict__ sel, float* __restrict__ nm,
                          float* __restrict__ gate, int* __restrict__ tie_list,
                          int* __restrict__ tie_cnt, int n) {
    int i = blockIdx.x * blockDim.x + threadIdx.x;
    if (i >= n) return;
    unsigned Tkey = (unsigned)sel[2];
    unsigned u = key_u(keys[i]);
    float v = 0.f;
    if (u > Tkey) v = 1.f;
    else if (u == Tkey) { int p = atomicAdd(tie_cnt, 1); tie_list[p] = i; }
    nm[i] = v;
    gate[i] = v * scores[i];
}

__global__ void topk_ties(const float* __restrict__ scores, const int* __restrict__ sel,
                          const int* __restrict__ tie_list, const int* __restrict__ tie_cnt,
                          float* __restrict__ nm, float* __restrict__ gate) {
    int cnt = *tie_cnt;
    int need = sel[3];
    for (int j = threadIdx.x; j < cnt; j += blockDim.x) {
        int idx = tie_list[j];
        int rank = 0;
        for (int k2 = 0; k2 < cnt; ++k2) rank += (tie_list[k2] < idx) ? 1 : 0;
        if (rank < need) { nm[idx] = 1.f; gate[idx] = scores[idx]; }
    }
}

// ---------------- selected-row compaction (order-independent) ----------------
__global__ void compact_kernel(const float* __restrict__ nm, int* __restrict__ idx,
                               int* __restrict__ cnt, int n) {
    int i = blockIdx.x * blockDim.x + threadIdx.x;
    if (i < n && nm[i] != 0.f) {
        int p = atomicAdd(cnt, 1);
        idx[p] = i;
    }
}

// ---------------- adds ----------------
__global__ void add_mask_kernel(float* __restrict__ A, const float* __restrict__ B,
                                const float* __restrict__ mask, int n4) {
    int i = blockIdx.x * blockDim.x + threadIdx.x;
    if (i < n4) {
        float4 a = ((float4*)A)[i];
        float4 b = ((const float4*)B)[i];
        if (mask && mask[i >> 6] == 0.f) { a.x = 0.f; a.y = 0.f; a.z = 0.f; a.w = 0.f; }
        a.x += b.x; a.y += b.y; a.z += b.z; a.w += b.w;
        ((float4*)A)[i] = a;
    }
}

extern "C" void kernel_launch(void* const* d_in, const int* in_sizes, int n_in,
                              void* d_out, int out_size, void* d_ws, size_t ws_size,
                              hipStream_t stream) {
    const int n = in_sizes[0] / 128;   // 50000
    const int E = in_sizes[1];         // 800000
    const int NPAD = ((n + 63) / 64) * 64;
    const int K1 = 25000, K2 = 12500;

    const float* features = (const float*)d_in[0];
    const int* src = (const int*)d_in[1];
    const int* dst = (const int*)d_in[2];
    const float* W_embed = (const float*)d_in[3];
    const float* b_embed = (const float*)d_in[4];
    const float* W_enc0  = (const float*)d_in[5];
    const float* b_enc0  = (const float*)d_in[6];
    const float* W_enc1  = (const float*)d_in[7];
    const float* b_enc1  = (const float*)d_in[8];
    const float* W_p0    = (const float*)d_in[9];
    const float* b_p0    = (const float*)d_in[10];
    const float* W_p1    = (const float*)d_in[11];
    const float* b_p1    = (const float*)d_in[12];
    const float* W_bot   = (const float*)d_in[13];
    const float* b_bot   = (const float*)d_in[14];
    const float* W_dec0  = (const float*)d_in[15];
    const float* b_dec0  = (const float*)d_in[16];
    const float* W_dec1  = (const float*)d_in[17];
    const float* b_dec1  = (const float*)d_in[18];
    float* out_f = (float*)d_out;

    char* ws = (char*)d_ws;
    size_t off = 0;
    auto alloc = [&](size_t bytes) -> void* {
        void* p = ws + off;
        off += (bytes + 255) & ~(size_t)255;
        return p;
    };
    (void)alloc(256);  // pad (R2 'flag' slot)
    int* row_ptr  = (int*)alloc((size_t)(n + 1) * 4);
    int* cursor   = (int*)alloc((size_t)n * 4);
    int* col      = (int*)alloc((size_t)E * 4);
    int* deg_out_i= (int*)alloc((size_t)n * 4);
    int* deg_in_i = (int*)alloc((size_t)n * 4);
    float* so_m1  = (float*)alloc((size_t)n * 4);
    float* si_m1  = (float*)alloc((size_t)n * 4);
    float* so_m2  = (float*)alloc((size_t)n * 4);
    float* si_m2  = (float*)alloc((size_t)n * 4);
    float* sarr   = (float*)alloc((size_t)n * 4);
    float* tarr   = (float*)alloc((size_t)n * 4);
    float* scores1= (float*)alloc((size_t)n * 4);
    float* keys1  = (float*)alloc((size_t)n * 4);
    float* scores2= (float*)alloc((size_t)n * 4);
    float* keys2  = (float*)alloc((size_t)n * 4);
    float* nm1    = (float*)alloc((size_t)n * 4);
    float* gate1  = (float*)alloc((size_t)n * 4);
    float* nm2    = (float*)alloc((size_t)n * 4);
    float* gate2  = (float*)alloc((size_t)n * 4);
    size_t big = (size_t)NPAD * 256 * 4;
    float* A = (float*)alloc(big);
    float* B = (float*)alloc(big);
    float* C = (float*)alloc(big);
    float* D = (float*)alloc(big);
    // ---- tail ----
    int* rhist    = (int*)alloc(65536 * 4);
    int* sel      = (int*)alloc(256);
    int* tie_cnt  = (int*)alloc(256);
    int* tie_list = (int*)alloc((size_t)n * 4);
    float* s0     = (float*)alloc((size_t)n * 4);
    float* t0     = (float*)alloc((size_t)n * 4);
    int* idx1     = (int*)alloc((size_t)n * 4);
    int* idx2     = (int*)alloc((size_t)n * 4);
    int* ccnt     = (int*)alloc(256);
    bool fast = (off <= ws_size);

    dim3 blk(256);
    int gE = (E + 255) / 256;
    int gN = (n + 255) / 256;
    int gAgg256 = (n + 3) / 4;
    int gAgg128 = (n + 7) / 8;
    int gScore = (n + 3) / 4;
    dim3 gemm_g(NPAD / 64, 2);          // Nn=256 -> 2 col-tiles of 128
    dim3 gemm_g128(NPAD / 64, 1);       // Nn=128 -> 1 col-tile
    dim3 gemm_gK1((K1 + 63) / 64, 2);
    dim3 gemm_gK2((K2 + 63) / 64, 2);
    int gAdd = (n * 64 + 255) / 256;

    auto run_topk = [&](const float* keys, const float* scores, float* nm, float* gate, int K) {
        if (fast) {
            hipMemsetAsync(rhist, 0, 65536 * 4, stream);
            topk_hist1<<<gN, blk, 0, stream>>>(keys, n, rhist);
            topk_scan1<<<1, 1024, 0, stream>>>(rhist, K, sel);
            hipMemsetAsync(rhist, 0, 65536 * 4, stream);
            topk_hist2<<<gN, blk, 0, stream>>>(keys, n, sel, rhist);
            topk_scan2<<<1, 1024, 0, stream>>>(rhist, sel, tie_cnt);
            topk_mark<<<gN, blk, 0, stream>>>(keys, scores, sel, nm, gate, tie_list, tie_cnt, n);
            topk_ties<<<1, 256, 0, stream>>>(scores, sel, tie_list, tie_cnt, nm, gate);
        } else {
            topk_kernel<<<1, 1024, 0, stream>>>(keys, scores, nm, gate, n, K);
        }
    };
    float* sF = fast ? s0 : sarr;
    float* tF = fast ? t0 : tarr;

    // ---- CSR build ----
    hipMemsetAsync(deg_out_i, 0, (size_t)n * 4, stream);
    hipMemsetAsync(deg_in_i, 0, (size_t)n * 4, stream);
    hist_kernel<<<gE, blk, 0, stream>>>(src, dst, deg_out_i, deg_in_i, E);
    scan_kernel<<<1, 1024, 0, stream>>>(deg_in_i, row_ptr, cursor, n);
    fill_kernel<<<gE, blk, 0, stream>>>(src, dst, cursor, col, E);
    sort_rows_kernel<<<gN, blk, 0, stream>>>(row_ptr, col, n);

    // ---- full-graph degree scales (once) ----
    scale_full_kernel<<<gN, blk, 0, stream>>>(deg_out_i, deg_in_i, sF, tF, n);

    // ---- embed GCN (full graph) -> A ----
    agg_feat_128_kernel<<<gAgg128, blk, 0, stream>>>(row_ptr, col, features, sF, tF, D, n);
    gemm_kernel<true><<<gemm_g, blk, 0, stream>>>(D, W_embed, b_embed, nullptr, nullptr, A, n, 128, 256);

    // ---- enc0 (full graph); hidden0 = B ----
    agg_f32_256_kernel<false><<<gAgg256, blk, 0, stream>>>(row_ptr, col, A, sF, tF, D, n);
    gemm_kernel<true><<<gemm_g, blk, 0, stream>>>(D, W_enc0, b_enc0, nullptr, nullptr, B, n, 256, 256);

    // ---- pool0 ----
    score_kernel<<<gScore, blk, 0, stream>>>(B, W_p0, b_p0, nullptr, scores1, keys1, n);
    run_topk(keys1, scores1, nm1, gate1, K1);
    if (fast) {
        hipMemsetAsync(ccnt, 0, 4, stream);
        compact_kernel<<<gN, blk, 0, stream>>>(nm1, idx1, ccnt, n);
    }

    // ---- enc1 (mask m1, gated input); hidden1 = C ----
    hipMemsetAsync(so_m1, 0, (size_t)n * 4, stream);
    out_deg_mask_kernel<<<gE, blk, 0, stream>>>(src, dst, nm1, so_m1, E);
    in_deg_mask_kernel<<<gN, blk, 0, stream>>>(row_ptr, col, nm1, si_m1, n);
    scale_mask_kernel<<<gN, blk, 0, stream>>>(gate1, nm1, so_m1, si_m1, sarr, tarr, n);
    agg_f32_256_kernel<true><<<gAgg256, blk, 0, stream>>>(row_ptr, col, B, sarr, tarr, D, n);
    if (fast)
        gemm_rows_kernel<true><<<gemm_gK1, blk, 0, stream>>>(D, W_enc1, b_enc1, idx1, K1, C, 256, 256);
    else
        gemm_kernel<true><<<gemm_g, blk, 0, stream>>>(D, W_enc1, b_enc1, nm1, nullptr, C, n, 256, 256);

    // ---- pool1 ----
    score_kernel<<<gScore, blk, 0, stream>>>(C, W_p1, b_p1, nm1, scores2, keys2, n);
    run_topk(keys2, scores2, nm2, gate2, K2);
    if (fast) {
        hipMemsetAsync(ccnt + 1, 0, 4, stream);
        compact_kernel<<<gN, blk, 0, stream>>>(nm2, idx2, ccnt + 1, n);
    }

    // ---- bottleneck (mask m2, gated input) -> A ----
    hipMemsetAsync(so_m2, 0, (size_t)n * 4, stream);
    out_deg_mask_kernel<<<gE, blk, 0, stream>>>(src, dst, nm2, so_m2, E);
    in_deg_mask_kernel<<<gN, blk, 0, stream>>>(row_ptr, col, nm2, si_m2, n);
    scale_mask_kernel<<<gN, blk, 0, stream>>>(gate2, nm2, so_m2, si_m2, sarr, tarr, n);
    agg_f32_256_kernel<true><<<gAgg256, blk, 0, stream>>>(row_ptr, col, C, sarr, tarr, D, n);
    if (fast)
        gemm_rows_kernel<true><<<gemm_gK2, blk, 0, stream>>>(D, W_bot, b_bot, idx2, K2, A, 256, 256);
    else
        gemm_kernel<true><<<gemm_g, blk, 0, stream>>>(D, W_bot, b_bot, nm2, nullptr, A, n, 256, 256);

    // ---- dec0: h = (m2? bot : 0) + hidden1, GCN mask m1 -> A ----
    add_mask_kernel<<<gAdd, blk, 0, stream>>>(A, C, fast ? nm2 : nullptr, n * 64);
    scale_mask_kernel<<<gN, blk, 0, stream>>>(nm1, nm1, so_m1, si_m1, sarr, tarr, n);
    agg_f32_256_kernel<true><<<gAgg256, blk, 0, stream>>>(row_ptr, col, A, sarr, tarr, D, n);
    if (fast)
        gemm_rows_kernel<true><<<gemm_gK1, blk, 0, stream>>>(D, W_dec0, b_dec0, idx1, K1, A, 256, 256);
    else
        gemm_kernel<true><<<gemm_g, blk, 0, stream>>>(D, W_dec0, b_dec0, nm1, nullptr, A, n, 256, 256);

    // ---- dec1 (reordered, final layer): h = (m1? dec0 : 0) + hidden0;
    //      P = (s0 .* h) @ W_dec1 -> C;  out_v = t0[v]*sum_N(v) P + b_dec1
    add_mask_kernel<<<gAdd, blk, 0, stream>>>(A, B, fast ? nm1 : nullptr, n * 64);
    if (!fast)
        scale_full_kernel<<<gN, blk, 0, stream>>>(deg_out_i, deg_in_i, sarr, tarr, n);
    gemm_kernel<false><<<gemm_g128, blk, 0, stream>>>(A, W_dec1, nullptr, nullptr, sF, C, n, 256, 128);
    agg_bias_128_kernel<<<gAgg128, blk, 0, stream>>>(row_ptr, col, C, tF, b_dec1, out_f, n);

    (void)n_in; (void)out_size;
}